// Round 1
// baseline (2304.852 us; speedup 1.0000x reference)
//
#include <hip/hip_runtime.h>
#include <hip/hip_bf16.h>

// ---------------- problem constants ----------------
#define DMODEL 512
#define NH     8
#define DHEAD  64
#define DFF    2048
#define NLAYER 6
#define BB     8
#define TT     1024
#define NTOK   (BB*TT)   // 8192 rows

typedef __bf16  bf16x8  __attribute__((ext_vector_type(8)));
typedef float   float4v __attribute__((ext_vector_type(4)));
typedef short   short4v __attribute__((ext_vector_type(4)));
typedef short   short8v __attribute__((ext_vector_type(8)));

__device__ __forceinline__ unsigned short f2bf(float f) {
    __hip_bfloat16 h = __float2bfloat16(f);
    return *reinterpret_cast<unsigned short*>(&h);
}

// async global->LDS, 16B per lane. LDS base must be wave-uniform; HW adds lane*16.
__device__ __forceinline__ void gl_lds16(const void* g, void* l) {
    __builtin_amdgcn_global_load_lds((const __attribute__((address_space(1))) void*)g,
                                     (__attribute__((address_space(3))) void*)l, 16, 0, 0);
}

// ---------------- weight transpose + fp32->bf16 ----------------
// src: [L][K][N] fp32, dst: [L][N][K] bf16. grid (K/64, N/64, L), block 256.
__global__ __launch_bounds__(256) void transpose_conv_kernel(
    const float* __restrict__ W, unsigned short* __restrict__ Wt, int K, int N)
{
    __shared__ float tile[64][65];
    const float* src = W + (size_t)blockIdx.z * K * N;
    unsigned short* dst = Wt + (size_t)blockIdx.z * K * N;
    const int k0 = blockIdx.x * 64, n0 = blockIdx.y * 64;
    const int tid = threadIdx.x;
#pragma unroll
    for (int rep = 0; rep < 16; ++rep) {
        int idx = rep * 256 + tid;
        int r = idx >> 6, c = idx & 63;
        tile[r][c] = src[(size_t)(k0 + r) * N + n0 + c];
    }
    __syncthreads();
#pragma unroll
    for (int rep = 0; rep < 16; ++rep) {
        int idx = rep * 256 + tid;
        int r = idx >> 6, c = idx & 63;
        dst[(size_t)(n0 + r) * K + k0 + c] = f2bf(tile[c][r]);
    }
}

// ---------------- fp32 -> bf16 convert (vectorized) ----------------
__global__ __launch_bounds__(256) void conv_bf16_kernel(
    const float* __restrict__ in, unsigned short* __restrict__ o)
{
    int i = (blockIdx.x * 256 + threadIdx.x) * 4;
    float4v v = *(const float4v*)(in + i);
    short4v w;
    w[0] = (short)f2bf(v[0]); w[1] = (short)f2bf(v[1]);
    w[2] = (short)f2bf(v[2]); w[3] = (short)f2bf(v[3]);
    *(short4v*)(o + i) = w;
}

// ---------------- embedding + sinusoidal PE ----------------
__global__ __launch_bounds__(256) void embed_kernel(
    const int* __restrict__ dec, const float* __restrict__ emb,
    float* __restrict__ x, unsigned short* __restrict__ xb)
{
    const int row = blockIdx.x;            // 0..8191
    const int t = row & (TT - 1);
    const int tid = threadIdx.x;
    const int tok = dec[row];
#pragma unroll
    for (int rep = 0; rep < 2; ++rep) {
        int c = tid + rep * 256;
        float e = (tok != 0) ? emb[(size_t)tok * DMODEL + c] : 0.f;
        int j = c >> 1;
        float freq = __expf(-(float)(2 * j) * (9.210340371976184f / 512.f));
        float ang = (float)t * freq;
        float pe = (c & 1) ? cosf(ang) : sinf(ang);
        float v = e + pe;
        x[(size_t)row * DMODEL + c] = v;
        xb[(size_t)row * DMODEL + c] = f2bf(v);
    }
}

// ---------------- residual add + LayerNorm (weight=1, bias=0) ----------------
__global__ __launch_bounds__(256) void add_ln_kernel(
    const float* __restrict__ a, const float* __restrict__ rsd,
    float* __restrict__ xo, unsigned short* __restrict__ xb)
{
    const int row = blockIdx.x;
    const int tid = threadIdx.x;
    const float* ar = a + (size_t)row * DMODEL;
    const float* rr = rsd + (size_t)row * DMODEL;
    float v0 = ar[tid] + rr[tid];
    float v1 = ar[tid + 256] + rr[tid + 256];
    float s = v0 + v1, sq = v0 * v0 + v1 * v1;
#pragma unroll
    for (int o = 1; o < 64; o <<= 1) { s += __shfl_xor(s, o); sq += __shfl_xor(sq, o); }
    __shared__ float red[8];
    const int wv = tid >> 6, lane = tid & 63;
    if (lane == 0) { red[wv] = s; red[wv + 4] = sq; }
    __syncthreads();
    s = red[0] + red[1] + red[2] + red[3];
    sq = red[4] + red[5] + red[6] + red[7];
    float mu = s * (1.f / 512.f);
    float var = sq * (1.f / 512.f) - mu * mu;
    float rstd = rsqrtf(var + 1e-5f);
    float y0 = (v0 - mu) * rstd, y1 = (v1 - mu) * rstd;
    float* xr = xo + (size_t)row * DMODEL;
    unsigned short* br = xb + (size_t)row * DMODEL;
    xr[tid] = y0; xr[tid + 256] = y1;
    br[tid] = f2bf(y0); br[tid + 256] = f2bf(y1);
}

// ---------------- bf16 GEMM: C[M,N] = A[M,K] * Bt[N,K]^T ----------------
// m97 structure: 128x128 tile, BK=32, 4 waves as 2x2, each wave 4x4 MFMA 16x16x32.
// EPI: 0 = fp32 out; 1 = relu -> bf16 out; 2 = bf16 scatter to [B,H,T,64].
template <int EPI>
__global__ __launch_bounds__(256) void gemm_bt(
    const unsigned short* __restrict__ A,
    const unsigned short* __restrict__ Bt,
    float* __restrict__ Cf,
    unsigned short* __restrict__ Cb,
    int M, int N, int K)
{
    __shared__ __attribute__((aligned(16))) short As[128 * 32];
    __shared__ __attribute__((aligned(16))) short Bs[128 * 32];
    const int tid = threadIdx.x;
    const int lane = tid & 63, wv = tid >> 6;
    const int quad = lane >> 4, l15 = lane & 15;
    const int m0 = blockIdx.x * 128, n0 = blockIdx.y * 128;
    const int wm = wv & 1, wn = wv >> 1;

    float4v acc[4][4];
#pragma unroll
    for (int i = 0; i < 4; ++i)
#pragma unroll
        for (int j = 0; j < 4; ++j) acc[i][j] = (float4v){0.f, 0.f, 0.f, 0.f};

    for (int k0 = 0; k0 < K; k0 += 32) {
#pragma unroll
        for (int i = 0; i < 2; ++i) {
            const int inst = wv * 2 + i;              // 0..7
            const int off = inst * 1024 + lane * 16;  // byte offset this lane covers
            const int row = off >> 6;                 // 64B per tile row
            const int cb = off & 63;
            gl_lds16((const char*)(A + (size_t)(m0 + row) * K + k0) + cb, (char*)As + inst * 1024);
            gl_lds16((const char*)(Bt + (size_t)(n0 + row) * K + k0) + cb, (char*)Bs + inst * 1024);
        }
        __syncthreads();
        bf16x8 a[4], b[4];
#pragma unroll
        for (int i = 0; i < 4; ++i) a[i] = *(const bf16x8*)&As[(wm * 64 + i * 16 + l15) * 32 + quad * 8];
#pragma unroll
        for (int j = 0; j < 4; ++j) b[j] = *(const bf16x8*)&Bs[(wn * 64 + j * 16 + l15) * 32 + quad * 8];
#pragma unroll
        for (int i = 0; i < 4; ++i)
#pragma unroll
            for (int j = 0; j < 4; ++j)
                acc[i][j] = __builtin_amdgcn_mfma_f32_16x16x32_bf16(a[i], b[j], acc[i][j], 0, 0, 0);
        __syncthreads();
    }

#pragma unroll
    for (int i = 0; i < 4; ++i) {
        const int row_base = m0 + wm * 64 + i * 16 + quad * 4;
#pragma unroll
        for (int j = 0; j < 4; ++j) {
            const int col = n0 + wn * 64 + j * 16 + l15;
#pragma unroll
            for (int r = 0; r < 4; ++r) {
                const int row = row_base + r;
                const float v = acc[i][j][r];
                if (EPI == 0) {
                    Cf[(size_t)row * N + col] = v;
                } else if (EPI == 1) {
                    Cb[(size_t)row * N + col] = f2bf(fmaxf(v, 0.f));
                } else {
                    const int b_ = row >> 10, t = row & (TT - 1);
                    const int h = col >> 6, d = col & 63;
                    Cb[(((size_t)(b_ * NH + h)) * TT + t) * DHEAD + d] = f2bf(v);
                }
            }
        }
    }
}

// ---------------- flash attention: Q[B,H,T,64] x K,V[B,H,Tk,64] -> ctx bf16 [B,T,512] ----------------
// Per block: one (b,h), 64 Q rows. Wave wv owns Q rows wv*16..+15.
// S^T = K*Q^T (MFMA, C-layout row=key col=q), online softmax per q (lane-resident),
// P routed through LDS (C-layout -> A-layout), V staged transposed for PV B-operand.
template <bool CAUSAL>
__global__ __launch_bounds__(256) void attn_kernel(
    const unsigned short* __restrict__ Q,
    const unsigned short* __restrict__ Kb,
    const unsigned short* __restrict__ Vb,
    const int* __restrict__ tokens,   // [B,Tk]; token==0 => masked key
    unsigned short* __restrict__ ctx, // [B,T,512] bf16
    int T, int Tk)
{
    __shared__ __attribute__((aligned(16))) short Ks[64 * 64];
    __shared__ __attribute__((aligned(16))) short Vt[64 * 64];     // [d][key]
    __shared__ __attribute__((aligned(16))) short Pl[4][16 * 72];  // per wave [q][key], pad 72
    __shared__ __attribute__((aligned(16))) float alphas[4][16];
    __shared__ __attribute__((aligned(16))) float lsum[4][16];
    __shared__ int kmask[64];

    const int tid = threadIdx.x, lane = tid & 63, wv = tid >> 6;
    const int quad = lane >> 4, l15 = lane & 15;
    const int qt = blockIdx.x;
    const int bh = blockIdx.y;
    const int b = bh >> 3, h = bh & 7;
    const size_t kvbase = (size_t)bh * Tk * DHEAD;
    const size_t qbase = (size_t)bh * T * DHEAD;

    const int q_local = wv * 16 + l15;
    const int q_global = qt * 64 + q_local;

    // Q fragments (B-operand for S^T): stay in registers across the whole KV loop
    const bf16x8 qf0 = *(const bf16x8*)&Q[qbase + (size_t)q_global * DHEAD + quad * 8];
    const bf16x8 qf1 = *(const bf16x8*)&Q[qbase + (size_t)q_global * DHEAD + 32 + quad * 8];

    float4v O[4];
#pragma unroll
    for (int j = 0; j < 4; ++j) O[j] = (float4v){0.f, 0.f, 0.f, 0.f};
    float m = -INFINITY, l = 0.f;

    const int nkt = CAUSAL ? (qt + 1) : (Tk >> 6);
    for (int kt = 0; kt < nkt; ++kt) {
        __syncthreads();
        // stage K tile [64 keys][64 d] (rows contiguous, 128B each)
#pragma unroll
        for (int i = 0; i < 2; ++i) {
            const int inst = wv * 2 + i;
            const int off = inst * 1024 + lane * 16;
            const int row = off >> 7;
            const int cb = off & 127;
            gl_lds16((const char*)(Kb + kvbase + (size_t)(kt * 64 + row) * DHEAD) + cb,
                     (char*)Ks + inst * 1024);
        }
        // stage V transposed: Vt[d][key]; ushort2 writes -> 2-way (free) bank pattern
        {
            const int key0 = (lane & 31) * 2;
            const int d0 = (lane >> 5) * 8 + wv * 16;
            const unsigned short* vp = Vb + kvbase + (size_t)(kt * 64 + key0) * DHEAD + d0;
            short8v r0 = *(const short8v*)(vp);
            short8v r1 = *(const short8v*)(vp + DHEAD);
#pragma unroll
            for (int j = 0; j < 8; ++j) {
                unsigned int pk = (unsigned int)(unsigned short)r0[j] |
                                  ((unsigned int)(unsigned short)r1[j] << 16);
                *(unsigned int*)&Vt[(d0 + j) * 64 + key0] = pk;
            }
        }
        if (tid < 64) kmask[tid] = (tokens[(size_t)b * Tk + kt * 64 + tid] == 0) ? 1 : 0;
        __syncthreads();

        // S^T = K * Q^T  (A = K rows, B = Q rows)
        float4v st[4];
#pragma unroll
        for (int i = 0; i < 4; ++i) {
            bf16x8 kf0 = *(const bf16x8*)&Ks[(i * 16 + l15) * 64 + quad * 8];
            bf16x8 kf1 = *(const bf16x8*)&Ks[(i * 16 + l15) * 64 + 32 + quad * 8];
            float4v z = (float4v){0.f, 0.f, 0.f, 0.f};
            z = __builtin_amdgcn_mfma_f32_16x16x32_bf16(kf0, qf0, z, 0, 0, 0);
            z = __builtin_amdgcn_mfma_f32_16x16x32_bf16(kf1, qf1, z, 0, 0, 0);
            st[i] = z;
        }

        // mask (exact replacement with -1e9, matching reference) + online softmax
        float sv[16];
        float smax = -INFINITY;
#pragma unroll
        for (int i = 0; i < 4; ++i)
#pragma unroll
            for (int r = 0; r < 4; ++r) {
                const int key_local = i * 16 + quad * 4 + r;
                const int key_g = kt * 64 + key_local;
                bool msk = (kmask[key_local] != 0) || (CAUSAL && key_g > q_global);
                float s = msk ? -1e9f : st[i][r] * 0.125f;
                sv[i * 4 + r] = s;
                smax = fmaxf(smax, s);
            }
        smax = fmaxf(smax, __shfl_xor(smax, 16));
        smax = fmaxf(smax, __shfl_xor(smax, 32));
        const float mnew = fmaxf(m, smax);
        const float alpha = __expf(m - mnew);
        float tsum = 0.f;
#pragma unroll
        for (int i = 0; i < 16; ++i) { float pv = __expf(sv[i] - mnew); sv[i] = pv; tsum += pv; }
        tsum += __shfl_xor(tsum, 16);
        tsum += __shfl_xor(tsum, 32);
        l = l * alpha + tsum;
        m = mnew;

        // write P^T (bf16) to LDS in A-operand-friendly layout: Pl[q][key]
#pragma unroll
        for (int i = 0; i < 4; ++i) {
            short4v pw;
#pragma unroll
            for (int r = 0; r < 4; ++r) pw[r] = (short)f2bf(sv[i * 4 + r]);
            *(short4v*)&Pl[wv][l15 * 72 + i * 16 + quad * 4] = pw;
        }
        if (lane < 16) alphas[wv][lane] = alpha;
        __syncthreads();

        // PV: O[q][d] += P[q][key] * V[key][d]
        const float4v aw = *(const float4v*)&alphas[wv][quad * 4];
        const bf16x8 p0 = *(const bf16x8*)&Pl[wv][l15 * 72 + quad * 8];
        const bf16x8 p1 = *(const bf16x8*)&Pl[wv][l15 * 72 + 32 + quad * 8];
#pragma unroll
        for (int j = 0; j < 4; ++j) {
            bf16x8 v0f = *(const bf16x8*)&Vt[(j * 16 + l15) * 64 + quad * 8];
            bf16x8 v1f = *(const bf16x8*)&Vt[(j * 16 + l15) * 64 + 32 + quad * 8];
            float4v o = O[j] * aw;
            o = __builtin_amdgcn_mfma_f32_16x16x32_bf16(p0, v0f, o, 0, 0, 0);
            o = __builtin_amdgcn_mfma_f32_16x16x32_bf16(p1, v1f, o, 0, 0, 0);
            O[j] = o;
        }
    }

    if (lane < 16) lsum[wv][lane] = l;
    __syncthreads();
    const float4v lw = *(const float4v*)&lsum[wv][quad * 4];
#pragma unroll
    for (int j = 0; j < 4; ++j)
#pragma unroll
        for (int r = 0; r < 4; ++r) {
            const int qrow = qt * 64 + wv * 16 + quad * 4 + r;
            ctx[((size_t)b * T + qrow) * DMODEL + h * DHEAD + j * 16 + l15] =
                f2bf(O[j][r] / lw[r]);
        }
}

// ---------------- host ----------------
extern "C" void kernel_launch(void* const* d_in, const int* in_sizes, int n_in,
                              void* d_out, int out_size, void* d_ws, size_t ws_size,
                              hipStream_t stream)
{
    const int* dec = (const int*)d_in[0];
    const int* enc = (const int*)d_in[1];
    const float* enc_out = (const float*)d_in[2];
    const float* emb = (const float*)d_in[3];
    const float* Wq_s = (const float*)d_in[4];
    const float* Wk_s = (const float*)d_in[5];
    const float* Wv_s = (const float*)d_in[6];
    const float* Wo_s = (const float*)d_in[7];
    const float* Wq_c = (const float*)d_in[8];
    const float* Wk_c = (const float*)d_in[9];
    const float* Wv_c = (const float*)d_in[10];
    const float* Wo_c = (const float*)d_in[11];
    const float* W1 = (const float*)d_in[12];
    const float* W2 = (const float*)d_in[13];
    float* out = (float*)d_out;

    char* p = (char*)d_ws;
    auto carve = [&](size_t bytes) -> char* {
        char* r = p;
        p += (bytes + 255) & ~(size_t)255;
        return r;
    };
    const size_t ACT = (size_t)NTOK * DMODEL;
    unsigned short* xb   = (unsigned short*)carve(ACT * 2);
    float* x             = (float*)carve(ACT * 4);
    float* tmp1          = (float*)carve(ACT * 4);
    unsigned short* Qb   = (unsigned short*)carve(ACT * 2);
    unsigned short* Kbuf = (unsigned short*)carve(ACT * 2);
    unsigned short* Vbuf = (unsigned short*)carve(ACT * 2);
    unsigned short* ctxb = (unsigned short*)carve(ACT * 2);
    unsigned short* encb = (unsigned short*)carve(ACT * 2);
    unsigned short* h1   = (unsigned short*)carve((size_t)NTOK * DFF * 2);
    const size_t WSML = (size_t)NLAYER * 512 * 512;  // elems per small weight type
    const size_t WBIG = (size_t)NLAYER * 512 * 2048;
    unsigned short* wqsT = (unsigned short*)carve(WSML * 2);
    unsigned short* wksT = (unsigned short*)carve(WSML * 2);
    unsigned short* wvsT = (unsigned short*)carve(WSML * 2);
    unsigned short* wosT = (unsigned short*)carve(WSML * 2);
    unsigned short* wqcT = (unsigned short*)carve(WSML * 2);
    unsigned short* wkcT = (unsigned short*)carve(WSML * 2);
    unsigned short* wvcT = (unsigned short*)carve(WSML * 2);
    unsigned short* wocT = (unsigned short*)carve(WSML * 2);
    unsigned short* w1T  = (unsigned short*)carve(WBIG * 2);
    unsigned short* w2T  = (unsigned short*)carve(WBIG * 2);

    // weights: transpose + convert (per launch; ws is re-poisoned each call)
    transpose_conv_kernel<<<dim3(8, 8, NLAYER), 256, 0, stream>>>(Wq_s, wqsT, 512, 512);
    transpose_conv_kernel<<<dim3(8, 8, NLAYER), 256, 0, stream>>>(Wk_s, wksT, 512, 512);
    transpose_conv_kernel<<<dim3(8, 8, NLAYER), 256, 0, stream>>>(Wv_s, wvsT, 512, 512);
    transpose_conv_kernel<<<dim3(8, 8, NLAYER), 256, 0, stream>>>(Wo_s, wosT, 512, 512);
    transpose_conv_kernel<<<dim3(8, 8, NLAYER), 256, 0, stream>>>(Wq_c, wqcT, 512, 512);
    transpose_conv_kernel<<<dim3(8, 8, NLAYER), 256, 0, stream>>>(Wk_c, wkcT, 512, 512);
    transpose_conv_kernel<<<dim3(8, 8, NLAYER), 256, 0, stream>>>(Wv_c, wvcT, 512, 512);
    transpose_conv_kernel<<<dim3(8, 8, NLAYER), 256, 0, stream>>>(Wo_c, wocT, 512, 512);
    transpose_conv_kernel<<<dim3(8, 32, NLAYER), 256, 0, stream>>>(W1, w1T, 512, 2048);
    transpose_conv_kernel<<<dim3(32, 8, NLAYER), 256, 0, stream>>>(W2, w2T, 2048, 512);
    conv_bf16_kernel<<<(int)(ACT / 1024), 256, 0, stream>>>(enc_out, encb);
    embed_kernel<<<NTOK, 256, 0, stream>>>(dec, emb, x, xb);

    for (int lyr = 0; lyr < NLAYER; ++lyr) {
        const size_t osml = (size_t)lyr * 512 * 512;
        const size_t obig = (size_t)lyr * 512 * 2048;
        const unsigned short* wq = wqsT + osml;
        const unsigned short* wk = wksT + osml;
        const unsigned short* wvv = wvsT + osml;
        const unsigned short* wo = wosT + osml;
        const unsigned short* wqc = wqcT + osml;
        const unsigned short* wkc = wkcT + osml;
        const unsigned short* wvc = wvcT + osml;
        const unsigned short* woc = wocT + osml;
        const unsigned short* w1 = w1T + obig;
        const unsigned short* w2 = w2T + obig;

        // ---- self attention ----
        gemm_bt<2><<<dim3(64, 4), 256, 0, stream>>>(xb, wq, nullptr, Qb, NTOK, 512, 512);
        gemm_bt<2><<<dim3(64, 4), 256, 0, stream>>>(xb, wk, nullptr, Kbuf, NTOK, 512, 512);
        gemm_bt<2><<<dim3(64, 4), 256, 0, stream>>>(xb, wvv, nullptr, Vbuf, NTOK, 512, 512);
        attn_kernel<true><<<dim3(TT / 64, BB * NH), 256, 0, stream>>>(Qb, Kbuf, Vbuf, dec, ctxb, TT, TT);
        gemm_bt<0><<<dim3(64, 4), 256, 0, stream>>>(ctxb, wo, tmp1, nullptr, NTOK, 512, 512);
        add_ln_kernel<<<NTOK, 256, 0, stream>>>(tmp1, x, x, xb);

        // ---- cross attention ----
        gemm_bt<2><<<dim3(64, 4), 256, 0, stream>>>(xb, wqc, nullptr, Qb, NTOK, 512, 512);
        gemm_bt<2><<<dim3(64, 4), 256, 0, stream>>>(encb, wkc, nullptr, Kbuf, NTOK, 512, 512);
        gemm_bt<2><<<dim3(64, 4), 256, 0, stream>>>(encb, wvc, nullptr, Vbuf, NTOK, 512, 512);
        attn_kernel<false><<<dim3(TT / 64, BB * NH), 256, 0, stream>>>(Qb, Kbuf, Vbuf, enc, ctxb, TT, TT);
        gemm_bt<0><<<dim3(64, 4), 256, 0, stream>>>(ctxb, woc, tmp1, nullptr, NTOK, 512, 512);
        add_ln_kernel<<<NTOK, 256, 0, stream>>>(tmp1, x, x, xb);

        // ---- FFN ----
        gemm_bt<1><<<dim3(64, 16), 256, 0, stream>>>(xb, w1, nullptr, h1, NTOK, 2048, 512);
        gemm_bt<0><<<dim3(64, 4), 256, 0, stream>>>(h1, w2, tmp1, nullptr, NTOK, 512, 2048);
        float* xo = (lyr == NLAYER - 1) ? out : x;
        add_ln_kernel<<<NTOK, 256, 0, stream>>>(tmp1, x, xo, xb);
    }
    (void)in_sizes; (void)n_in; (void)out_size; (void)ws_size;
}

// Round 2
// 1889.122 us; speedup vs baseline: 1.2201x; 1.2201x over previous
//
#include <hip/hip_runtime.h>
#include <hip/hip_bf16.h>

// ---------------- problem constants ----------------
#define DMODEL 512
#define NH     8
#define DHEAD  64
#define DFF    2048
#define NLAYER 6
#define BB     8
#define TT     1024
#define NTOK   (BB*TT)                 // 8192 rows
#define ACTE   ((size_t)NTOK*DMODEL)   // 4,194,304 elements

typedef __bf16  bf16x8  __attribute__((ext_vector_type(8)));
typedef float   float4v __attribute__((ext_vector_type(4)));
typedef short   short4v __attribute__((ext_vector_type(4)));
typedef short   short8v __attribute__((ext_vector_type(8)));

__device__ __forceinline__ unsigned short f2bf(float f) {
    __hip_bfloat16 h = __float2bfloat16(f);
    return *reinterpret_cast<unsigned short*>(&h);
}

// async global->LDS, 16B/lane. LDS base wave-uniform; HW adds lane*16.
// Global address is PER-LANE -> we use it to write a swizzled LDS layout for free.
__device__ __forceinline__ void gl_lds16(const void* g, void* l) {
    __builtin_amdgcn_global_load_lds((const __attribute__((address_space(1))) void*)g,
                                     (__attribute__((address_space(3))) void*)l, 16, 0, 0);
}
__device__ __forceinline__ void wave_order() { __builtin_amdgcn_wave_barrier(); }

// ---------------- weight transpose + fp32->bf16 ----------------
// src: [L][K][N] fp32 (layer stride K*N); dst row (rowOff+n) of a [?, K] bf16 matrix,
// per-layer dst stride dstL. grid (K/64, N/64, L), block 256.
__global__ __launch_bounds__(256) void transpose_conv_kernel(
    const float* __restrict__ W, unsigned short* __restrict__ Wt, int K, int N,
    size_t dstL, int rowOff)
{
    __shared__ float tile[64][65];
    const float* src = W + (size_t)blockIdx.z * K * N;
    unsigned short* dst = Wt + (size_t)blockIdx.z * dstL;
    const int k0 = blockIdx.x * 64, n0 = blockIdx.y * 64;
    const int tid = threadIdx.x;
#pragma unroll
    for (int rep = 0; rep < 16; ++rep) {
        int idx = rep * 256 + tid;
        int r = idx >> 6, c = idx & 63;
        tile[r][c] = src[(size_t)(k0 + r) * N + n0 + c];
    }
    __syncthreads();
#pragma unroll
    for (int rep = 0; rep < 16; ++rep) {
        int idx = rep * 256 + tid;
        int r = idx >> 6, c = idx & 63;
        dst[(size_t)(rowOff + n0 + r) * K + k0 + c] = f2bf(tile[c][r]);
    }
}

// ---------------- fp32 -> bf16 convert ----------------
__global__ __launch_bounds__(256) void conv_bf16_kernel(
    const float* __restrict__ in, unsigned short* __restrict__ o)
{
    int i = (blockIdx.x * 256 + threadIdx.x) * 4;
    float4v v = *(const float4v*)(in + i);
    short4v w;
    w[0] = (short)f2bf(v[0]); w[1] = (short)f2bf(v[1]);
    w[2] = (short)f2bf(v[2]); w[3] = (short)f2bf(v[3]);
    *(short4v*)(o + i) = w;
}

// ---------------- embedding + sinusoidal PE (bf16 out only) ----------------
__global__ __launch_bounds__(256) void embed_kernel(
    const int* __restrict__ dec, const float* __restrict__ emb,
    unsigned short* __restrict__ xb)
{
    const int row = blockIdx.x;            // 0..8191
    const int t = row & (TT - 1);
    const int tid = threadIdx.x;
    const int tok = dec[row];
#pragma unroll
    for (int rep = 0; rep < 2; ++rep) {
        int c = tid + rep * 256;
        float e = (tok != 0) ? emb[(size_t)tok * DMODEL + c] : 0.f;
        int j = c >> 1;
        float freq = __expf(-(float)(2 * j) * (9.210340371976184f / 512.f));
        float ang = (float)t * freq;
        float pe = (c & 1) ? cosf(ang) : sinf(ang);
        xb[(size_t)row * DMODEL + c] = f2bf(e + pe);
    }
}

// ---------------- residual add + LayerNorm, wave-per-row ----------------
// y = LN(tmp + bf16(xb));  writes xb (bf16) or xout (fp32, final layer).
__global__ __launch_bounds__(256) void add_ln2(
    const float* __restrict__ t, unsigned short* __restrict__ xb,
    float* __restrict__ xout)
{
    const int lane = threadIdx.x & 63;
    const int row = blockIdx.x * 4 + (threadIdx.x >> 6);
    const int c = lane * 8;
    const float* tr = t + (size_t)row * DMODEL + c;
    float4v t0 = *(const float4v*)tr;
    float4v t1 = *(const float4v*)(tr + 4);
    bf16x8 rb = *(const bf16x8*)(xb + (size_t)row * DMODEL + c);
    float v[8];
#pragma unroll
    for (int k = 0; k < 4; ++k) { v[k] = t0[k] + (float)rb[k]; v[4 + k] = t1[k] + (float)rb[4 + k]; }
    float s = 0.f, sq = 0.f;
#pragma unroll
    for (int k = 0; k < 8; ++k) { s += v[k]; sq += v[k] * v[k]; }
#pragma unroll
    for (int o = 1; o < 64; o <<= 1) { s += __shfl_xor(s, o); sq += __shfl_xor(sq, o); }
    float mu = s * (1.f / 512.f);
    float var = sq * (1.f / 512.f) - mu * mu;
    float rstd = rsqrtf(var + 1e-5f);
    if (xout) {
        float4v y0, y1;
#pragma unroll
        for (int k = 0; k < 4; ++k) { y0[k] = (v[k] - mu) * rstd; y1[k] = (v[4 + k] - mu) * rstd; }
        *(float4v*)(xout + (size_t)row * DMODEL + c) = y0;
        *(float4v*)(xout + (size_t)row * DMODEL + c + 4) = y1;
    } else {
        short8v w;
#pragma unroll
        for (int k = 0; k < 8; ++k) w[k] = (short)f2bf((v[k] - mu) * rstd);
        *(short8v*)(xb + (size_t)row * DMODEL + c) = w;
    }
}

// ---------------- bf16 GEMM: C[M,N] = A[M,K] * Bt[N,K]^T ----------------
// 128x128 tile, BK=32, 2x2 waves, 4x4 MFMA 16x16x32 per wave.
// LDS stored in XOR-swizzled 16B chunks: chunk (row,cb) at slot cb ^ ((row>>1)&3)
// -> fragment ds_read_b128 is 2-way (free) instead of 8-way conflicted.
// EPI: 0 fp32 out; 1 relu->bf16; 2 head-scatter (which=col>>9) to [which][B,H,T,64];
//      3 all-layer KV scatter (layer=col>>10, which=(col>>9)&1).
template <int EPI>
__global__ __launch_bounds__(256) void gemm_bt(
    const unsigned short* __restrict__ A,
    const unsigned short* __restrict__ Bt,
    float* __restrict__ Cf,
    unsigned short* __restrict__ Cb,
    int M, int N, int K)
{
    __shared__ __attribute__((aligned(16))) short As[128 * 32];
    __shared__ __attribute__((aligned(16))) short Bs[128 * 32];
    const int tid = threadIdx.x;
    const int lane = tid & 63, wv = tid >> 6;
    const int quad = lane >> 4, l15 = lane & 15;
    const int m0 = blockIdx.x * 128, n0 = blockIdx.y * 128;
    const int wm = wv & 1, wn = wv >> 1;

    float4v acc[4][4];
#pragma unroll
    for (int i = 0; i < 4; ++i)
#pragma unroll
        for (int j = 0; j < 4; ++j) acc[i][j] = (float4v){0.f, 0.f, 0.f, 0.f};

    for (int k0 = 0; k0 < K; k0 += 32) {
#pragma unroll
        for (int i = 0; i < 2; ++i) {
            const int inst = wv * 2 + i;                 // 0..7, 1KB each
            const int row = inst * 16 + (lane >> 2);     // tile row this lane fills
            const int cb = (lane & 3) ^ ((row >> 1) & 3); // logical 16B chunk (swizzle)
            gl_lds16(A + (size_t)(m0 + row) * K + k0 + cb * 8, (char*)As + inst * 1024);
            gl_lds16(Bt + (size_t)(n0 + row) * K + k0 + cb * 8, (char*)Bs + inst * 1024);
        }
        __syncthreads();
        bf16x8 a[4], b[4];
#pragma unroll
        for (int i = 0; i < 4; ++i) {
            const int r = wm * 64 + i * 16 + l15;
            const int st = quad ^ ((r >> 1) & 3);
            a[i] = *(const bf16x8*)&As[r * 32 + st * 8];
        }
#pragma unroll
        for (int j = 0; j < 4; ++j) {
            const int r = wn * 64 + j * 16 + l15;
            const int st = quad ^ ((r >> 1) & 3);
            b[j] = *(const bf16x8*)&Bs[r * 32 + st * 8];
        }
#pragma unroll
        for (int i = 0; i < 4; ++i)
#pragma unroll
            for (int j = 0; j < 4; ++j)
                acc[i][j] = __builtin_amdgcn_mfma_f32_16x16x32_bf16(a[i], b[j], acc[i][j], 0, 0, 0);
        __syncthreads();
    }

#pragma unroll
    for (int i = 0; i < 4; ++i) {
        const int row_base = m0 + wm * 64 + i * 16 + quad * 4;
#pragma unroll
        for (int j = 0; j < 4; ++j) {
            const int col = n0 + wn * 64 + j * 16 + l15;
#pragma unroll
            for (int r = 0; r < 4; ++r) {
                const int row = row_base + r;
                const float v = acc[i][j][r];
                if (EPI == 0) {
                    Cf[(size_t)row * N + col] = v;
                } else if (EPI == 1) {
                    Cb[(size_t)row * N + col] = f2bf(fmaxf(v, 0.f));
                } else if (EPI == 2) {
                    const int which = col >> 9;
                    const int b_ = row >> 10, t = row & (TT - 1);
                    const int h = (col >> 6) & 7, d = col & 63;
                    Cb[(size_t)which * ACTE + (((size_t)(b_ * NH + h)) * TT + t) * DHEAD + d] = f2bf(v);
                } else {
                    const int layer = col >> 10, which = (col >> 9) & 1;
                    const int b_ = row >> 10, t = row & (TT - 1);
                    const int h = (col >> 6) & 7, d = col & 63;
                    Cb[(size_t)(layer * 2 + which) * ACTE +
                       (((size_t)(b_ * NH + h)) * TT + t) * DHEAD + d] = f2bf(v);
                }
            }
        }
    }
}

// ---------------- flash attention ----------------
// Grid (8, B*H). Each block handles TWO q-tiles sharing staged KV:
//   causal: (p, 15-p) -> constant 17 tile-units/block (perfect balance)
//   cross:  (p, p+8)
// Ks/Vt stored XOR-swizzled (chunk cb at slot cb^(row&7)) -> conflict-free frag reads.
// 2 barriers per KV tile; P/alpha routing is per-wave (LDS in-order per wave).
template <bool CAUSAL>
__global__ __launch_bounds__(256) void attn_kernel(
    const unsigned short* __restrict__ Q,
    const unsigned short* __restrict__ Kb,
    const unsigned short* __restrict__ Vb,
    const int* __restrict__ tokens,   // [B,Tk]; token==0 => masked key
    unsigned short* __restrict__ ctx) // [B,T,512] bf16
{
    __shared__ __attribute__((aligned(16))) short Ks[64 * 64];   // [key][d] swizzled
    __shared__ __attribute__((aligned(16))) short Vt[64 * 64];   // [d][key] swizzled
    __shared__ __attribute__((aligned(16))) short Pl[4][16 * 72];
    __shared__ __attribute__((aligned(16))) float alphas[4][16];
    __shared__ int kmask[64];

    const int tid = threadIdx.x, lane = tid & 63, wv = tid >> 6;
    const int quad = lane >> 4, l15 = lane & 15;
    const int p = blockIdx.x;
    const int bh = blockIdx.y;
    const int b = bh >> 3, h = bh & 7;
    const size_t kvbase = (size_t)bh * TT * DHEAD;

    const int qt0 = p;
    const int qt1 = CAUSAL ? (15 - p) : (p + 8);
    const int qg0 = qt0 * 64 + wv * 16 + l15;
    const int qg1 = qt1 * 64 + wv * 16 + l15;

    const bf16x8 qa0 = *(const bf16x8*)&Q[kvbase + (size_t)qg0 * DHEAD + quad * 8];
    const bf16x8 qa1 = *(const bf16x8*)&Q[kvbase + (size_t)qg0 * DHEAD + 32 + quad * 8];
    const bf16x8 qb0 = *(const bf16x8*)&Q[kvbase + (size_t)qg1 * DHEAD + quad * 8];
    const bf16x8 qb1 = *(const bf16x8*)&Q[kvbase + (size_t)qg1 * DHEAD + 32 + quad * 8];

    float4v O0[4], O1[4];
#pragma unroll
    for (int j = 0; j < 4; ++j) { O0[j] = (float4v){0.f,0.f,0.f,0.f}; O1[j] = (float4v){0.f,0.f,0.f,0.f}; }
    float m0_ = -INFINITY, l0_ = 0.f, m1_ = -INFINITY, l1_ = 0.f;

    int kt = 0;  // visible to lambda
    auto process = [&](const bf16x8& qf0, const bf16x8& qf1, int qg,
                       float& m, float& l, float4v* O) {
        // S^T = K * Q^T : D[key][q]
        float4v st[4];
#pragma unroll
        for (int i = 0; i < 4; ++i) {
            const int row = i * 16 + l15;
            const int s0 = quad ^ (row & 7);
            const int s1 = (4 + quad) ^ (row & 7);
            bf16x8 kf0 = *(const bf16x8*)&Ks[row * 64 + s0 * 8];
            bf16x8 kf1 = *(const bf16x8*)&Ks[row * 64 + s1 * 8];
            float4v z = (float4v){0.f, 0.f, 0.f, 0.f};
            z = __builtin_amdgcn_mfma_f32_16x16x32_bf16(kf0, qf0, z, 0, 0, 0);
            z = __builtin_amdgcn_mfma_f32_16x16x32_bf16(kf1, qf1, z, 0, 0, 0);
            st[i] = z;
        }
        float sv[16], smax = -INFINITY;
#pragma unroll
        for (int i = 0; i < 4; ++i)
#pragma unroll
            for (int r = 0; r < 4; ++r) {
                const int key_local = i * 16 + quad * 4 + r;
                const int key_g = kt * 64 + key_local;
                bool msk = (kmask[key_local] != 0) || (CAUSAL && key_g > qg);
                float s = msk ? -1e9f : st[i][r] * 0.125f;
                sv[i * 4 + r] = s;
                smax = fmaxf(smax, s);
            }
        smax = fmaxf(smax, __shfl_xor(smax, 16));
        smax = fmaxf(smax, __shfl_xor(smax, 32));
        const float mnew = fmaxf(m, smax);
        const float alpha = __expf(m - mnew);
        float tsum = 0.f;
#pragma unroll
        for (int i = 0; i < 16; ++i) { float pv = __expf(sv[i] - mnew); sv[i] = pv; tsum += pv; }
        tsum += __shfl_xor(tsum, 16);
        tsum += __shfl_xor(tsum, 32);
        l = l * alpha + tsum;
        m = mnew;
        wave_order();  // order vs previous group's Pl/alphas reads
#pragma unroll
        for (int i = 0; i < 4; ++i) {
            short4v pw;
#pragma unroll
            for (int r = 0; r < 4; ++r) pw[r] = (short)f2bf(sv[i * 4 + r]);
            *(short4v*)&Pl[wv][l15 * 72 + i * 16 + quad * 4] = pw;
        }
        if (lane < 16) alphas[wv][lane] = alpha;
        wave_order();  // LDS in-order per wave; pin compiler order
        const float4v aw = *(const float4v*)&alphas[wv][quad * 4];
        const bf16x8 p0 = *(const bf16x8*)&Pl[wv][l15 * 72 + quad * 8];
        const bf16x8 p1 = *(const bf16x8*)&Pl[wv][l15 * 72 + 32 + quad * 8];
#pragma unroll
        for (int j = 0; j < 4; ++j) {
            const int row = j * 16 + l15;
            const int s0 = quad ^ (row & 7);
            const int s1 = (4 + quad) ^ (row & 7);
            bf16x8 v0f = *(const bf16x8*)&Vt[row * 64 + s0 * 8];
            bf16x8 v1f = *(const bf16x8*)&Vt[row * 64 + s1 * 8];
            float4v o = O[j] * aw;
            o = __builtin_amdgcn_mfma_f32_16x16x32_bf16(p0, v0f, o, 0, 0, 0);
            o = __builtin_amdgcn_mfma_f32_16x16x32_bf16(p1, v1f, o, 0, 0, 0);
            O[j] = o;
        }
    };

    const int nkt = CAUSAL ? (qt1 + 1) : 16;
    for (kt = 0; kt < nkt; ++kt) {
        __syncthreads();
        // stage K (swizzled via per-lane global source)
#pragma unroll
        for (int i = 0; i < 2; ++i) {
            const int inst = wv * 2 + i;
            const int row = inst * 8 + (lane >> 3);
            const int cb = (lane & 7) ^ (row & 7);
            gl_lds16(Kb + kvbase + (size_t)(kt * 64 + row) * DHEAD + cb * 8,
                     (char*)Ks + inst * 1024);
        }
        // stage V transposed (swizzled writes, conflict-free)
        {
            const int key0 = (lane & 31) * 2;
            const int d0 = (lane >> 5) * 8 + wv * 16;
            const unsigned short* vp = Vb + kvbase + (size_t)(kt * 64 + key0) * DHEAD + d0;
            short8v r0 = *(const short8v*)vp;
            short8v r1 = *(const short8v*)(vp + DHEAD);
            const int kc = key0 >> 3, ko = key0 & 7;
#pragma unroll
            for (int j = 0; j < 8; ++j) {
                const int d = d0 + j;
                unsigned pk = (unsigned)(unsigned short)r0[j] |
                              ((unsigned)(unsigned short)r1[j] << 16);
                *(unsigned*)&Vt[d * 64 + ((kc ^ (d & 7)) << 3) + ko] = pk;
            }
        }
        if (tid < 64) kmask[tid] = (tokens[(size_t)b * TT + kt * 64 + tid] == 0);
        __syncthreads();

        if (!CAUSAL || kt <= qt0) process(qa0, qa1, qg0, m0_, l0_, O0);
        process(qb0, qb1, qg1, m1_, l1_, O1);
    }

    auto finalize = [&](float l, float4v* O, int qt) {
        wave_order();
        if (lane < 16) alphas[wv][lane] = l;
        wave_order();
        const float4v lw = *(const float4v*)&alphas[wv][quad * 4];
#pragma unroll
        for (int j = 0; j < 4; ++j)
#pragma unroll
            for (int r = 0; r < 4; ++r) {
                const int qrow = qt * 64 + wv * 16 + quad * 4 + r;
                ctx[((size_t)b * TT + qrow) * DMODEL + h * DHEAD + j * 16 + l15] =
                    f2bf(O[j][r] / lw[r]);
            }
    };
    finalize(l0_, O0, qt0);
    finalize(l1_, O1, qt1);
}

// ---------------- host ----------------
extern "C" void kernel_launch(void* const* d_in, const int* in_sizes, int n_in,
                              void* d_out, int out_size, void* d_ws, size_t ws_size,
                              hipStream_t stream)
{
    const int* dec = (const int*)d_in[0];
    const int* enc = (const int*)d_in[1];
    const float* enc_out = (const float*)d_in[2];
    const float* emb = (const float*)d_in[3];
    const float* Wq_s = (const float*)d_in[4];
    const float* Wk_s = (const float*)d_in[5];
    const float* Wv_s = (const float*)d_in[6];
    const float* Wo_s = (const float*)d_in[7];
    const float* Wq_c = (const float*)d_in[8];
    const float* Wk_c = (const float*)d_in[9];
    const float* Wv_c = (const float*)d_in[10];
    const float* Wo_c = (const float*)d_in[11];
    const float* W1 = (const float*)d_in[12];
    const float* W2 = (const float*)d_in[13];
    float* out = (float*)d_out;

    char* p = (char*)d_ws;
    auto carve = [&](size_t bytes) -> char* {
        char* r = p;
        p += (bytes + 255) & ~(size_t)255;
        return r;
    };
    unsigned short* xb   = (unsigned short*)carve(ACTE * 2);
    float* tmp1          = (float*)carve(ACTE * 4);
    unsigned short* qkvb = (unsigned short*)carve(3 * ACTE * 2);  // Q|K|V contiguous
    unsigned short* ctxb = (unsigned short*)carve(ACTE * 2);
    unsigned short* encb = (unsigned short*)carve(ACTE * 2);
    unsigned short* h1   = (unsigned short*)carve((size_t)NTOK * DFF * 2);
    unsigned short* wqkvT = (unsigned short*)carve((size_t)NLAYER * 1536 * 512 * 2);
    unsigned short* woT   = (unsigned short*)carve((size_t)NLAYER * 512 * 512 * 2);
    unsigned short* wqcT  = (unsigned short*)carve((size_t)NLAYER * 512 * 512 * 2);
    unsigned short* wkvcT = (unsigned short*)carve((size_t)NLAYER * 1024 * 512 * 2);
    unsigned short* wocT  = (unsigned short*)carve((size_t)NLAYER * 512 * 512 * 2);
    unsigned short* w1T   = (unsigned short*)carve((size_t)NLAYER * 2048 * 512 * 2);
    unsigned short* w2T   = (unsigned short*)carve((size_t)NLAYER * 512 * 2048 * 2);
    const size_t used = (size_t)(p - (char*)d_ws);
    const bool pre = (used + 12 * ACTE * 2 + 256) <= ws_size;  // all-layer cross K/V cache
    unsigned short* KVc = pre ? (unsigned short*)carve(12 * ACTE * 2) : nullptr;

    // weight prep
    transpose_conv_kernel<<<dim3(8, 8, NLAYER), 256, 0, stream>>>(Wq_s, wqkvT, 512, 512, (size_t)1536 * 512, 0);
    transpose_conv_kernel<<<dim3(8, 8, NLAYER), 256, 0, stream>>>(Wk_s, wqkvT, 512, 512, (size_t)1536 * 512, 512);
    transpose_conv_kernel<<<dim3(8, 8, NLAYER), 256, 0, stream>>>(Wv_s, wqkvT, 512, 512, (size_t)1536 * 512, 1024);
    transpose_conv_kernel<<<dim3(8, 8, NLAYER), 256, 0, stream>>>(Wo_s, woT, 512, 512, (size_t)512 * 512, 0);
    transpose_conv_kernel<<<dim3(8, 8, NLAYER), 256, 0, stream>>>(Wq_c, wqcT, 512, 512, (size_t)512 * 512, 0);
    transpose_conv_kernel<<<dim3(8, 8, NLAYER), 256, 0, stream>>>(Wk_c, wkvcT, 512, 512, (size_t)1024 * 512, 0);
    transpose_conv_kernel<<<dim3(8, 8, NLAYER), 256, 0, stream>>>(Wv_c, wkvcT, 512, 512, (size_t)1024 * 512, 512);
    transpose_conv_kernel<<<dim3(8, 8, NLAYER), 256, 0, stream>>>(Wo_c, wocT, 512, 512, (size_t)512 * 512, 0);
    transpose_conv_kernel<<<dim3(8, 32, NLAYER), 256, 0, stream>>>(W1, w1T, 512, 2048, (size_t)2048 * 512, 0);
    transpose_conv_kernel<<<dim3(32, 8, NLAYER), 256, 0, stream>>>(W2, w2T, 2048, 512, (size_t)512 * 2048, 0);
    conv_bf16_kernel<<<(int)(ACTE / 1024), 256, 0, stream>>>(enc_out, encb);
    embed_kernel<<<NTOK, 256, 0, stream>>>(dec, emb, xb);

    // cross K/V for ALL layers in one big GEMM (enc side is layer-invariant)
    if (pre)
        gemm_bt<3><<<dim3(64, 48), 256, 0, stream>>>(encb, wkvcT, nullptr, KVc, NTOK, 6144, 512);

    for (int lyr = 0; lyr < NLAYER; ++lyr) {
        const unsigned short* wqkv = wqkvT + (size_t)lyr * 1536 * 512;
        const unsigned short* wo   = woT + (size_t)lyr * 512 * 512;
        const unsigned short* wqc  = wqcT + (size_t)lyr * 512 * 512;
        const unsigned short* wkvc = wkvcT + (size_t)lyr * 1024 * 512;
        const unsigned short* woc  = wocT + (size_t)lyr * 512 * 512;
        const unsigned short* w1   = w1T + (size_t)lyr * 2048 * 512;
        const unsigned short* w2   = w2T + (size_t)lyr * 512 * 2048;

        // ---- self attention ----
        gemm_bt<2><<<dim3(64, 12), 256, 0, stream>>>(xb, wqkv, nullptr, qkvb, NTOK, 1536, 512);
        attn_kernel<true><<<dim3(8, BB * NH), 256, 0, stream>>>(
            qkvb, qkvb + ACTE, qkvb + 2 * ACTE, dec, ctxb);
        gemm_bt<0><<<dim3(64, 4), 256, 0, stream>>>(ctxb, wo, tmp1, nullptr, NTOK, 512, 512);
        add_ln2<<<NTOK / 4, 256, 0, stream>>>(tmp1, xb, nullptr);

        // ---- cross attention ----
        gemm_bt<2><<<dim3(64, 4), 256, 0, stream>>>(xb, wqc, nullptr, qkvb, NTOK, 512, 512);
        const unsigned short* Kc;
        if (pre) {
            Kc = KVc + (size_t)lyr * 2 * ACTE;
        } else {
            gemm_bt<2><<<dim3(64, 8), 256, 0, stream>>>(encb, wkvc, nullptr, qkvb + ACTE, NTOK, 1024, 512);
            Kc = qkvb + ACTE;
        }
        attn_kernel<false><<<dim3(8, BB * NH), 256, 0, stream>>>(
            qkvb, Kc, Kc + ACTE, enc, ctxb);
        gemm_bt<0><<<dim3(64, 4), 256, 0, stream>>>(ctxb, woc, tmp1, nullptr, NTOK, 512, 512);
        add_ln2<<<NTOK / 4, 256, 0, stream>>>(tmp1, xb, nullptr);

        // ---- FFN ----
        gemm_bt<1><<<dim3(64, 16), 256, 0, stream>>>(xb, w1, nullptr, h1, NTOK, 2048, 512);
        gemm_bt<0><<<dim3(64, 4), 256, 0, stream>>>(h1, w2, tmp1, nullptr, NTOK, 512, 2048);
        add_ln2<<<NTOK / 4, 256, 0, stream>>>(tmp1, xb, (lyr == NLAYER - 1) ? out : nullptr);
    }
    (void)in_sizes; (void)n_in; (void)out_size;
}

// Round 3
// 1755.320 us; speedup vs baseline: 1.3131x; 1.0762x over previous
//
#include <hip/hip_runtime.h>
#include <hip/hip_bf16.h>

// ---------------- problem constants ----------------
#define DMODEL 512
#define NH     8
#define DHEAD  64
#define DFF    2048
#define NLAYER 6
#define BB     8
#define TT     1024
#define NTOK   (BB*TT)                 // 8192 rows
#define ACTE   ((size_t)NTOK*DMODEL)   // 4,194,304 elements

typedef __bf16  bf16x8  __attribute__((ext_vector_type(8)));
typedef float   float4v __attribute__((ext_vector_type(4)));
typedef short   short4v __attribute__((ext_vector_type(4)));
typedef short   short8v __attribute__((ext_vector_type(8)));

__device__ __forceinline__ unsigned short f2bf(float f) {
    __hip_bfloat16 h = __float2bfloat16(f);
    return *reinterpret_cast<unsigned short*>(&h);
}

// async global->LDS, 16B/lane. LDS base wave-uniform; HW adds lane*16.
// Global address is PER-LANE -> we use it to write a swizzled LDS layout for free.
__device__ __forceinline__ void gl_lds16(const void* g, void* l) {
    __builtin_amdgcn_global_load_lds((const __attribute__((address_space(1))) void*)g,
                                     (__attribute__((address_space(3))) void*)l, 16, 0, 0);
}
__device__ __forceinline__ void wave_order() { __builtin_amdgcn_wave_barrier(); }

// ---------------- merged small-weight transpose (8 types x 6 layers) ----------------
// Each src is [6][512][512] fp32; dst row (rowOff+n) of a [?,512] bf16 matrix.
struct Tr8Args {
    const float* src[8];
    unsigned short* dst[8];
    int dstL[8];    // per-layer dst stride (elements)
    int rowOff[8];
};
__global__ __launch_bounds__(256) void transpose8_kernel(Tr8Args a)
{
    __shared__ float tile[64][65];
    const int type = blockIdx.z / 6, lyr = blockIdx.z % 6;
    const float* src = a.src[type] + (size_t)lyr * 512 * 512;
    unsigned short* dst = a.dst[type] + (size_t)lyr * a.dstL[type];
    const int rowOff = a.rowOff[type];
    const int k0 = blockIdx.x * 64, n0 = blockIdx.y * 64;
    const int tid = threadIdx.x;
#pragma unroll
    for (int rep = 0; rep < 16; ++rep) {
        int idx = rep * 256 + tid;
        int r = idx >> 6, c = idx & 63;
        tile[r][c] = src[(size_t)(k0 + r) * 512 + n0 + c];
    }
    __syncthreads();
#pragma unroll
    for (int rep = 0; rep < 16; ++rep) {
        int idx = rep * 256 + tid;
        int r = idx >> 6, c = idx & 63;
        dst[(size_t)(rowOff + n0 + r) * 512 + k0 + c] = f2bf(tile[c][r]);
    }
}

// ---------------- generic transpose (W1/W2) ----------------
__global__ __launch_bounds__(256) void transpose_conv_kernel(
    const float* __restrict__ W, unsigned short* __restrict__ Wt, int K, int N,
    size_t dstL, int rowOff)
{
    __shared__ float tile[64][65];
    const float* src = W + (size_t)blockIdx.z * K * N;
    unsigned short* dst = Wt + (size_t)blockIdx.z * dstL;
    const int k0 = blockIdx.x * 64, n0 = blockIdx.y * 64;
    const int tid = threadIdx.x;
#pragma unroll
    for (int rep = 0; rep < 16; ++rep) {
        int idx = rep * 256 + tid;
        int r = idx >> 6, c = idx & 63;
        tile[r][c] = src[(size_t)(k0 + r) * N + n0 + c];
    }
    __syncthreads();
#pragma unroll
    for (int rep = 0; rep < 16; ++rep) {
        int idx = rep * 256 + tid;
        int r = idx >> 6, c = idx & 63;
        dst[(size_t)(rowOff + n0 + r) * K + k0 + c] = f2bf(tile[c][r]);
    }
}

// ---------------- fp32 -> bf16 convert ----------------
__global__ __launch_bounds__(256) void conv_bf16_kernel(
    const float* __restrict__ in, unsigned short* __restrict__ o)
{
    int i = (blockIdx.x * 256 + threadIdx.x) * 4;
    float4v v = *(const float4v*)(in + i);
    short4v w;
    w[0] = (short)f2bf(v[0]); w[1] = (short)f2bf(v[1]);
    w[2] = (short)f2bf(v[2]); w[3] = (short)f2bf(v[3]);
    *(short4v*)(o + i) = w;
}

// ---------------- embedding + sinusoidal PE (bf16 out only) ----------------
__global__ __launch_bounds__(256) void embed_kernel(
    const int* __restrict__ dec, const float* __restrict__ emb,
    unsigned short* __restrict__ xb)
{
    const int row = blockIdx.x;            // 0..8191
    const int t = row & (TT - 1);
    const int tid = threadIdx.x;
    const int tok = dec[row];
#pragma unroll
    for (int rep = 0; rep < 2; ++rep) {
        int c = tid + rep * 256;
        float e = (tok != 0) ? emb[(size_t)tok * DMODEL + c] : 0.f;
        int j = c >> 1;
        float freq = __expf(-(float)(2 * j) * (9.210340371976184f / 512.f));
        float ang = (float)t * freq;
        float pe = (c & 1) ? cosf(ang) : sinf(ang);
        xb[(size_t)row * DMODEL + c] = f2bf(e + pe);
    }
}

// ---------------- residual add + LayerNorm, wave-per-row ----------------
// y = LN(t[0..ACTE) + t[ACTE..2*ACTE) + bf16(xb));  writes xb (bf16) or xout (fp32).
__global__ __launch_bounds__(256) void add_ln2(
    const float* __restrict__ t, unsigned short* __restrict__ xb,
    float* __restrict__ xout)
{
    const int lane = threadIdx.x & 63;
    const int row = blockIdx.x * 4 + (threadIdx.x >> 6);
    const size_t idx = (size_t)row * DMODEL + lane * 8;
    float4v t0 = *(const float4v*)(t + idx);
    float4v t1 = *(const float4v*)(t + idx + 4);
    float4v u0 = *(const float4v*)(t + ACTE + idx);
    float4v u1 = *(const float4v*)(t + ACTE + idx + 4);
    bf16x8 rb = *(const bf16x8*)(xb + idx);
    float v[8];
#pragma unroll
    for (int k = 0; k < 4; ++k) {
        v[k] = t0[k] + u0[k] + (float)rb[k];
        v[4 + k] = t1[k] + u1[k] + (float)rb[4 + k];
    }
    float s = 0.f, sq = 0.f;
#pragma unroll
    for (int k = 0; k < 8; ++k) { s += v[k]; sq += v[k] * v[k]; }
#pragma unroll
    for (int o = 1; o < 64; o <<= 1) { s += __shfl_xor(s, o); sq += __shfl_xor(sq, o); }
    float mu = s * (1.f / 512.f);
    float var = sq * (1.f / 512.f) - mu * mu;
    float rstd = rsqrtf(var + 1e-5f);
    if (xout) {
        float4v y0, y1;
#pragma unroll
        for (int k = 0; k < 4; ++k) { y0[k] = (v[k] - mu) * rstd; y1[k] = (v[4 + k] - mu) * rstd; }
        *(float4v*)(xout + idx) = y0;
        *(float4v*)(xout + idx + 4) = y1;
    } else {
        short8v w;
#pragma unroll
        for (int k = 0; k < 8; ++k) w[k] = (short)f2bf((v[k] - mu) * rstd);
        *(short8v*)(xb + idx) = w;
    }
}

// ---------------- bf16 GEMM: C[M,N] = A[M,K] * Bt[N,K]^T ----------------
// 128x128 tile, BK=32, 2x2 waves, 4x4 MFMA 16x16x32 per wave.
// LDS XOR-swizzled 16B chunks -> conflict-free ds_read_b128 fragment reads.
// SPLITK>1: blockIdx.z selects a K-slice; EPI0 writes partial to Cf + z*ACTE
// (all split users have M*N == ACTE).
// EPI: 0 fp32 out; 1 relu->bf16; 2 head-scatter (which=col>>9) to [which][B,H,T,64];
//      3 all-layer KV scatter (layer=col>>10, which=(col>>9)&1).
template <int EPI, int SPLITK = 1>
__global__ __launch_bounds__(256) void gemm_bt(
    const unsigned short* __restrict__ A,
    const unsigned short* __restrict__ Bt,
    float* __restrict__ Cf,
    unsigned short* __restrict__ Cb,
    int M, int N, int K)
{
    __shared__ __attribute__((aligned(16))) short As[128 * 32];
    __shared__ __attribute__((aligned(16))) short Bs[128 * 32];
    const int tid = threadIdx.x;
    const int lane = tid & 63, wv = tid >> 6;
    const int quad = lane >> 4, l15 = lane & 15;
    const int m0 = blockIdx.x * 128, n0 = blockIdx.y * 128;
    const int wm = wv & 1, wn = wv >> 1;

    float4v acc[4][4];
#pragma unroll
    for (int i = 0; i < 4; ++i)
#pragma unroll
        for (int j = 0; j < 4; ++j) acc[i][j] = (float4v){0.f, 0.f, 0.f, 0.f};

    const int Kc = K / SPLITK;
    const int kbeg = (SPLITK > 1) ? (int)blockIdx.z * Kc : 0;
    for (int k0 = kbeg; k0 < kbeg + Kc; k0 += 32) {
#pragma unroll
        for (int i = 0; i < 2; ++i) {
            const int inst = wv * 2 + i;                 // 0..7, 1KB each
            const int row = inst * 16 + (lane >> 2);     // tile row this lane fills
            const int cb = (lane & 3) ^ ((row >> 1) & 3); // swizzled 16B chunk
            gl_lds16(A + (size_t)(m0 + row) * K + k0 + cb * 8, (char*)As + inst * 1024);
            gl_lds16(Bt + (size_t)(n0 + row) * K + k0 + cb * 8, (char*)Bs + inst * 1024);
        }
        __syncthreads();
        bf16x8 a[4], b[4];
#pragma unroll
        for (int i = 0; i < 4; ++i) {
            const int r = wm * 64 + i * 16 + l15;
            const int st = quad ^ ((r >> 1) & 3);
            a[i] = *(const bf16x8*)&As[r * 32 + st * 8];
        }
#pragma unroll
        for (int j = 0; j < 4; ++j) {
            const int r = wn * 64 + j * 16 + l15;
            const int st = quad ^ ((r >> 1) & 3);
            b[j] = *(const bf16x8*)&Bs[r * 32 + st * 8];
        }
#pragma unroll
        for (int i = 0; i < 4; ++i)
#pragma unroll
            for (int j = 0; j < 4; ++j)
                acc[i][j] = __builtin_amdgcn_mfma_f32_16x16x32_bf16(a[i], b[j], acc[i][j], 0, 0, 0);
        __syncthreads();
    }

    const size_t zoff = (SPLITK > 1) ? (size_t)blockIdx.z * ACTE : 0;
#pragma unroll
    for (int i = 0; i < 4; ++i) {
        const int row_base = m0 + wm * 64 + i * 16 + quad * 4;
#pragma unroll
        for (int j = 0; j < 4; ++j) {
            const int col = n0 + wn * 64 + j * 16 + l15;
#pragma unroll
            for (int r = 0; r < 4; ++r) {
                const int row = row_base + r;
                const float v = acc[i][j][r];
                if (EPI == 0) {
                    Cf[zoff + (size_t)row * N + col] = v;
                } else if (EPI == 1) {
                    Cb[(size_t)row * N + col] = f2bf(fmaxf(v, 0.f));
                } else if (EPI == 2) {
                    const int which = col >> 9;
                    const int b_ = row >> 10, t = row & (TT - 1);
                    const int h = (col >> 6) & 7, d = col & 63;
                    Cb[(size_t)which * ACTE + (((size_t)(b_ * NH + h)) * TT + t) * DHEAD + d] = f2bf(v);
                } else {
                    const int layer = col >> 10, which = (col >> 9) & 1;
                    const int b_ = row >> 10, t = row & (TT - 1);
                    const int h = (col >> 6) & 7, d = col & 63;
                    Cb[(size_t)(layer * 2 + which) * ACTE +
                       (((size_t)(b_ * NH + h)) * TT + t) * DHEAD + d] = f2bf(v);
                }
            }
        }
    }
}

// ---------------- flash attention ----------------
// Grid (8, B*H). Each block handles TWO q-tiles sharing staged KV:
//   causal: (p, 15-p) -> constant 17 tile-units/block; cross: (p, p+8).
// Ks/Vt XOR-swizzled -> conflict-free frag reads. 2 barriers per KV tile.
template <bool CAUSAL>
__global__ __launch_bounds__(256) void attn_kernel(
    const unsigned short* __restrict__ Q,
    const unsigned short* __restrict__ Kb,
    const unsigned short* __restrict__ Vb,
    const int* __restrict__ tokens,   // [B,Tk]; token==0 => masked key
    unsigned short* __restrict__ ctx) // [B,T,512] bf16
{
    __shared__ __attribute__((aligned(16))) short Ks[64 * 64];   // [key][d] swizzled
    __shared__ __attribute__((aligned(16))) short Vt[64 * 64];   // [d][key] swizzled
    __shared__ __attribute__((aligned(16))) short Pl[4][16 * 72];
    __shared__ __attribute__((aligned(16))) float alphas[4][16];
    __shared__ int kmask[64];

    const int tid = threadIdx.x, lane = tid & 63, wv = tid >> 6;
    const int quad = lane >> 4, l15 = lane & 15;
    const int p = blockIdx.x;
    const int bh = blockIdx.y;
    const int b = bh >> 3, h = bh & 7;
    const size_t kvbase = (size_t)bh * TT * DHEAD;

    const int qt0 = p;
    const int qt1 = CAUSAL ? (15 - p) : (p + 8);
    const int qg0 = qt0 * 64 + wv * 16 + l15;
    const int qg1 = qt1 * 64 + wv * 16 + l15;

    const bf16x8 qa0 = *(const bf16x8*)&Q[kvbase + (size_t)qg0 * DHEAD + quad * 8];
    const bf16x8 qa1 = *(const bf16x8*)&Q[kvbase + (size_t)qg0 * DHEAD + 32 + quad * 8];
    const bf16x8 qb0 = *(const bf16x8*)&Q[kvbase + (size_t)qg1 * DHEAD + quad * 8];
    const bf16x8 qb1 = *(const bf16x8*)&Q[kvbase + (size_t)qg1 * DHEAD + 32 + quad * 8];

    float4v O0[4], O1[4];
#pragma unroll
    for (int j = 0; j < 4; ++j) { O0[j] = (float4v){0.f,0.f,0.f,0.f}; O1[j] = (float4v){0.f,0.f,0.f,0.f}; }
    float m0_ = -INFINITY, l0_ = 0.f, m1_ = -INFINITY, l1_ = 0.f;

    int kt = 0;
    auto process = [&](const bf16x8& qf0, const bf16x8& qf1, int qg,
                       float& m, float& l, float4v* O) {
        float4v st[4];
#pragma unroll
        for (int i = 0; i < 4; ++i) {
            const int row = i * 16 + l15;
            const int s0 = quad ^ (row & 7);
            const int s1 = (4 + quad) ^ (row & 7);
            bf16x8 kf0 = *(const bf16x8*)&Ks[row * 64 + s0 * 8];
            bf16x8 kf1 = *(const bf16x8*)&Ks[row * 64 + s1 * 8];
            float4v z = (float4v){0.f, 0.f, 0.f, 0.f};
            z = __builtin_amdgcn_mfma_f32_16x16x32_bf16(kf0, qf0, z, 0, 0, 0);
            z = __builtin_amdgcn_mfma_f32_16x16x32_bf16(kf1, qf1, z, 0, 0, 0);
            st[i] = z;
        }
        float sv[16], smax = -INFINITY;
#pragma unroll
        for (int i = 0; i < 4; ++i)
#pragma unroll
            for (int r = 0; r < 4; ++r) {
                const int key_local = i * 16 + quad * 4 + r;
                const int key_g = kt * 64 + key_local;
                bool msk = (kmask[key_local] != 0) || (CAUSAL && key_g > qg);
                float s = msk ? -1e9f : st[i][r] * 0.125f;
                sv[i * 4 + r] = s;
                smax = fmaxf(smax, s);
            }
        smax = fmaxf(smax, __shfl_xor(smax, 16));
        smax = fmaxf(smax, __shfl_xor(smax, 32));
        const float mnew = fmaxf(m, smax);
        const float alpha = __expf(m - mnew);
        float tsum = 0.f;
#pragma unroll
        for (int i = 0; i < 16; ++i) { float pv = __expf(sv[i] - mnew); sv[i] = pv; tsum += pv; }
        tsum += __shfl_xor(tsum, 16);
        tsum += __shfl_xor(tsum, 32);
        l = l * alpha + tsum;
        m = mnew;
        wave_order();
#pragma unroll
        for (int i = 0; i < 4; ++i) {
            short4v pw;
#pragma unroll
            for (int r = 0; r < 4; ++r) pw[r] = (short)f2bf(sv[i * 4 + r]);
            *(short4v*)&Pl[wv][l15 * 72 + i * 16 + quad * 4] = pw;
        }
        if (lane < 16) alphas[wv][lane] = alpha;
        wave_order();
        const float4v aw = *(const float4v*)&alphas[wv][quad * 4];
        const bf16x8 p0 = *(const bf16x8*)&Pl[wv][l15 * 72 + quad * 8];
        const bf16x8 p1 = *(const bf16x8*)&Pl[wv][l15 * 72 + 32 + quad * 8];
#pragma unroll
        for (int j = 0; j < 4; ++j) {
            const int row = j * 16 + l15;
            const int s0 = quad ^ (row & 7);
            const int s1 = (4 + quad) ^ (row & 7);
            bf16x8 v0f = *(const bf16x8*)&Vt[row * 64 + s0 * 8];
            bf16x8 v1f = *(const bf16x8*)&Vt[row * 64 + s1 * 8];
            float4v o = O[j] * aw;
            o = __builtin_amdgcn_mfma_f32_16x16x32_bf16(p0, v0f, o, 0, 0, 0);
            o = __builtin_amdgcn_mfma_f32_16x16x32_bf16(p1, v1f, o, 0, 0, 0);
            O[j] = o;
        }
    };

    const int nkt = CAUSAL ? (qt1 + 1) : 16;
    for (kt = 0; kt < nkt; ++kt) {
        __syncthreads();
#pragma unroll
        for (int i = 0; i < 2; ++i) {
            const int inst = wv * 2 + i;
            const int row = inst * 8 + (lane >> 3);
            const int cb = (lane & 7) ^ (row & 7);
            gl_lds16(Kb + kvbase + (size_t)(kt * 64 + row) * DHEAD + cb * 8,
                     (char*)Ks + inst * 1024);
        }
        {
            const int key0 = (lane & 31) * 2;
            const int d0 = (lane >> 5) * 8 + wv * 16;
            const unsigned short* vp = Vb + kvbase + (size_t)(kt * 64 + key0) * DHEAD + d0;
            short8v r0 = *(const short8v*)vp;
            short8v r1 = *(const short8v*)(vp + DHEAD);
            const int kc = key0 >> 3, ko = key0 & 7;
#pragma unroll
            for (int j = 0; j < 8; ++j) {
                const int d = d0 + j;
                unsigned pk = (unsigned)(unsigned short)r0[j] |
                              ((unsigned)(unsigned short)r1[j] << 16);
                *(unsigned*)&Vt[d * 64 + ((kc ^ (d & 7)) << 3) + ko] = pk;
            }
        }
        if (tid < 64) kmask[tid] = (tokens[(size_t)b * TT + kt * 64 + tid] == 0);
        __syncthreads();

        if (!CAUSAL || kt <= qt0) process(qa0, qa1, qg0, m0_, l0_, O0);
        process(qb0, qb1, qg1, m1_, l1_, O1);
    }

    auto finalize = [&](float l, float4v* O, int qt) {
        wave_order();
        if (lane < 16) alphas[wv][lane] = l;
        wave_order();
        const float4v lw = *(const float4v*)&alphas[wv][quad * 4];
#pragma unroll
        for (int j = 0; j < 4; ++j)
#pragma unroll
            for (int r = 0; r < 4; ++r) {
                const int qrow = qt * 64 + wv * 16 + quad * 4 + r;
                ctx[((size_t)b * TT + qrow) * DMODEL + h * DHEAD + j * 16 + l15] =
                    f2bf(O[j][r] / lw[r]);
            }
    };
    finalize(l0_, O0, qt0);
    finalize(l1_, O1, qt1);
}

// ---------------- host ----------------
extern "C" void kernel_launch(void* const* d_in, const int* in_sizes, int n_in,
                              void* d_out, int out_size, void* d_ws, size_t ws_size,
                              hipStream_t stream)
{
    const int* dec = (const int*)d_in[0];
    const int* enc = (const int*)d_in[1];
    const float* enc_out = (const float*)d_in[2];
    const float* emb = (const float*)d_in[3];
    const float* Wq_s = (const float*)d_in[4];
    const float* Wk_s = (const float*)d_in[5];
    const float* Wv_s = (const float*)d_in[6];
    const float* Wo_s = (const float*)d_in[7];
    const float* Wq_c = (const float*)d_in[8];
    const float* Wk_c = (const float*)d_in[9];
    const float* Wv_c = (const float*)d_in[10];
    const float* Wo_c = (const float*)d_in[11];
    const float* W1 = (const float*)d_in[12];
    const float* W2 = (const float*)d_in[13];
    float* out = (float*)d_out;

    char* p = (char*)d_ws;
    auto carve = [&](size_t bytes) -> char* {
        char* r = p;
        p += (bytes + 255) & ~(size_t)255;
        return r;
    };
    unsigned short* xb   = (unsigned short*)carve(ACTE * 2);
    float* tmp1          = (float*)carve(2 * ACTE * 4);           // 2 split-K partial slices
    unsigned short* qkvb = (unsigned short*)carve(3 * ACTE * 2);  // Q|K|V contiguous
    unsigned short* ctxb = (unsigned short*)carve(ACTE * 2);
    unsigned short* encb = (unsigned short*)carve(ACTE * 2);
    unsigned short* h1   = (unsigned short*)carve((size_t)NTOK * DFF * 2);
    unsigned short* wqkvT = (unsigned short*)carve((size_t)NLAYER * 1536 * 512 * 2);
    unsigned short* woT   = (unsigned short*)carve((size_t)NLAYER * 512 * 512 * 2);
    unsigned short* wqcT  = (unsigned short*)carve((size_t)NLAYER * 512 * 512 * 2);
    unsigned short* wkvcT = (unsigned short*)carve((size_t)NLAYER * 1024 * 512 * 2);
    unsigned short* wocT  = (unsigned short*)carve((size_t)NLAYER * 512 * 512 * 2);
    unsigned short* w1T   = (unsigned short*)carve((size_t)NLAYER * 2048 * 512 * 2);
    unsigned short* w2T   = (unsigned short*)carve((size_t)NLAYER * 512 * 2048 * 2);
    const size_t used = (size_t)(p - (char*)d_ws);
    const bool pre = (used + 12 * ACTE * 2 + 256) <= ws_size;  // all-layer cross K/V cache
    unsigned short* KVc = pre ? (unsigned short*)carve(12 * ACTE * 2) : nullptr;

    // weight prep: 8 small transposes merged into one dispatch
    Tr8Args ta;
    ta.src[0] = Wq_s; ta.dst[0] = wqkvT; ta.dstL[0] = 1536 * 512; ta.rowOff[0] = 0;
    ta.src[1] = Wk_s; ta.dst[1] = wqkvT; ta.dstL[1] = 1536 * 512; ta.rowOff[1] = 512;
    ta.src[2] = Wv_s; ta.dst[2] = wqkvT; ta.dstL[2] = 1536 * 512; ta.rowOff[2] = 1024;
    ta.src[3] = Wo_s; ta.dst[3] = woT;   ta.dstL[3] = 512 * 512;  ta.rowOff[3] = 0;
    ta.src[4] = Wq_c; ta.dst[4] = wqcT;  ta.dstL[4] = 512 * 512;  ta.rowOff[4] = 0;
    ta.src[5] = Wk_c; ta.dst[5] = wkvcT; ta.dstL[5] = 1024 * 512; ta.rowOff[5] = 0;
    ta.src[6] = Wv_c; ta.dst[6] = wkvcT; ta.dstL[6] = 1024 * 512; ta.rowOff[6] = 512;
    ta.src[7] = Wo_c; ta.dst[7] = wocT;  ta.dstL[7] = 512 * 512;  ta.rowOff[7] = 0;
    transpose8_kernel<<<dim3(8, 8, 48), 256, 0, stream>>>(ta);
    transpose_conv_kernel<<<dim3(8, 32, NLAYER), 256, 0, stream>>>(W1, w1T, 512, 2048, (size_t)2048 * 512, 0);
    transpose_conv_kernel<<<dim3(32, 8, NLAYER), 256, 0, stream>>>(W2, w2T, 2048, 512, (size_t)512 * 2048, 0);
    conv_bf16_kernel<<<(int)(ACTE / 1024), 256, 0, stream>>>(enc_out, encb);
    embed_kernel<<<NTOK, 256, 0, stream>>>(dec, emb, xb);

    // cross K/V for ALL layers in one big GEMM (enc side is layer-invariant)
    if (pre)
        gemm_bt<3><<<dim3(64, 48), 256, 0, stream>>>(encb, wkvcT, nullptr, KVc, NTOK, 6144, 512);

    for (int lyr = 0; lyr < NLAYER; ++lyr) {
        const unsigned short* wqkv = wqkvT + (size_t)lyr * 1536 * 512;
        const unsigned short* wo   = woT + (size_t)lyr * 512 * 512;
        const unsigned short* wqc  = wqcT + (size_t)lyr * 512 * 512;
        const unsigned short* wkvc = wkvcT + (size_t)lyr * 1024 * 512;
        const unsigned short* woc  = wocT + (size_t)lyr * 512 * 512;
        const unsigned short* w1   = w1T + (size_t)lyr * 2048 * 512;
        const unsigned short* w2   = w2T + (size_t)lyr * 512 * 2048;

        // ---- self attention ----
        gemm_bt<2><<<dim3(64, 12), 256, 0, stream>>>(xb, wqkv, nullptr, qkvb, NTOK, 1536, 512);
        attn_kernel<true><<<dim3(8, BB * NH), 256, 0, stream>>>(
            qkvb, qkvb + ACTE, qkvb + 2 * ACTE, dec, ctxb);
        gemm_bt<0, 2><<<dim3(64, 4, 2), 256, 0, stream>>>(ctxb, wo, tmp1, nullptr, NTOK, 512, 512);
        add_ln2<<<NTOK / 4, 256, 0, stream>>>(tmp1, xb, nullptr);

        // ---- cross attention ----
        gemm_bt<2><<<dim3(64, 4), 256, 0, stream>>>(xb, wqc, nullptr, qkvb, NTOK, 512, 512);
        const unsigned short* Kc;
        if (pre) {
            Kc = KVc + (size_t)lyr * 2 * ACTE;
        } else {
            gemm_bt<2><<<dim3(64, 8), 256, 0, stream>>>(encb, wkvc, nullptr, qkvb + ACTE, NTOK, 1024, 512);
            Kc = qkvb + ACTE;
        }
        attn_kernel<false><<<dim3(8, BB * NH), 256, 0, stream>>>(
            qkvb, Kc, Kc + ACTE, enc, ctxb);
        gemm_bt<0, 2><<<dim3(64, 4, 2), 256, 0, stream>>>(ctxb, woc, tmp1, nullptr, NTOK, 512, 512);
        add_ln2<<<NTOK / 4, 256, 0, stream>>>(tmp1, xb, nullptr);

        // ---- FFN ----
        gemm_bt<1><<<dim3(64, 16), 256, 0, stream>>>(xb, w1, nullptr, h1, NTOK, 2048, 512);
        gemm_bt<0, 2><<<dim3(64, 4, 2), 256, 0, stream>>>(h1, w2, tmp1, nullptr, NTOK, 512, 2048);
        add_ln2<<<NTOK / 4, 256, 0, stream>>>(tmp1, xb, (lyr == NLAYER - 1) ? out : nullptr);
    }
    (void)in_sizes; (void)n_in; (void)out_size;
}

// Round 4
// 1688.550 us; speedup vs baseline: 1.3650x; 1.0395x over previous
//
#include <hip/hip_runtime.h>
#include <hip/hip_bf16.h>

// ---------------- problem constants ----------------
#define DMODEL 512
#define NH     8
#define DHEAD  64
#define DFF    2048
#define NLAYER 6
#define BB     8
#define TT     1024
#define NTOK   (BB*TT)                 // 8192 rows
#define ACTE   ((size_t)NTOK*DMODEL)   // 4,194,304 elements

typedef __bf16  bf16x8  __attribute__((ext_vector_type(8)));
typedef float   float4v __attribute__((ext_vector_type(4)));
typedef short   short4v __attribute__((ext_vector_type(4)));
typedef short   short8v __attribute__((ext_vector_type(8)));

__device__ __forceinline__ unsigned short f2bf(float f) {
    __hip_bfloat16 h = __float2bfloat16(f);
    return *reinterpret_cast<unsigned short*>(&h);
}

// async global->LDS, 16B/lane. LDS base wave-uniform; HW adds lane*16.
// Global address is PER-LANE -> used to write a swizzled LDS layout for free.
__device__ __forceinline__ void gl_lds16(const void* g, void* l) {
    __builtin_amdgcn_global_load_lds((const __attribute__((address_space(1))) void*)g,
                                     (__attribute__((address_space(3))) void*)l, 16, 0, 0);
}

// ---------------- merged small-weight transpose (8 types x 6 layers) ----------------
struct Tr8Args {
    const float* src[8];
    unsigned short* dst[8];
    int dstL[8];    // per-layer dst stride (elements)
    int rowOff[8];
};
__global__ __launch_bounds__(256) void transpose8_kernel(Tr8Args a)
{
    __shared__ float tile[64][65];
    const int type = blockIdx.z / 6, lyr = blockIdx.z % 6;
    const float* src = a.src[type] + (size_t)lyr * 512 * 512;
    unsigned short* dst = a.dst[type] + (size_t)lyr * a.dstL[type];
    const int rowOff = a.rowOff[type];
    const int k0 = blockIdx.x * 64, n0 = blockIdx.y * 64;
    const int tid = threadIdx.x;
#pragma unroll
    for (int rep = 0; rep < 16; ++rep) {
        int idx = rep * 256 + tid;
        int r = idx >> 6, c = idx & 63;
        tile[r][c] = src[(size_t)(k0 + r) * 512 + n0 + c];
    }
    __syncthreads();
#pragma unroll
    for (int rep = 0; rep < 16; ++rep) {
        int idx = rep * 256 + tid;
        int r = idx >> 6, c = idx & 63;
        dst[(size_t)(rowOff + n0 + r) * 512 + k0 + c] = f2bf(tile[c][r]);
    }
}

// ---------------- generic transpose (W1/W2) ----------------
__global__ __launch_bounds__(256) void transpose_conv_kernel(
    const float* __restrict__ W, unsigned short* __restrict__ Wt, int K, int N,
    size_t dstL, int rowOff)
{
    __shared__ float tile[64][65];
    const float* src = W + (size_t)blockIdx.z * K * N;
    unsigned short* dst = Wt + (size_t)blockIdx.z * dstL;
    const int k0 = blockIdx.x * 64, n0 = blockIdx.y * 64;
    const int tid = threadIdx.x;
#pragma unroll
    for (int rep = 0; rep < 16; ++rep) {
        int idx = rep * 256 + tid;
        int r = idx >> 6, c = idx & 63;
        tile[r][c] = src[(size_t)(k0 + r) * N + n0 + c];
    }
    __syncthreads();
#pragma unroll
    for (int rep = 0; rep < 16; ++rep) {
        int idx = rep * 256 + tid;
        int r = idx >> 6, c = idx & 63;
        dst[(size_t)(rowOff + n0 + r) * K + k0 + c] = f2bf(tile[c][r]);
    }
}

// ---------------- fp32 -> bf16 convert ----------------
__global__ __launch_bounds__(256) void conv_bf16_kernel(
    const float* __restrict__ in, unsigned short* __restrict__ o)
{
    int i = (blockIdx.x * 256 + threadIdx.x) * 4;
    float4v v = *(const float4v*)(in + i);
    short4v w;
    w[0] = (short)f2bf(v[0]); w[1] = (short)f2bf(v[1]);
    w[2] = (short)f2bf(v[2]); w[3] = (short)f2bf(v[3]);
    *(short4v*)(o + i) = w;
}

// ---------------- embedding + sinusoidal PE (bf16 out only) ----------------
__global__ __launch_bounds__(256) void embed_kernel(
    const int* __restrict__ dec, const float* __restrict__ emb,
    unsigned short* __restrict__ xb)
{
    const int row = blockIdx.x;            // 0..8191
    const int t = row & (TT - 1);
    const int tid = threadIdx.x;
    const int tok = dec[row];
#pragma unroll
    for (int rep = 0; rep < 2; ++rep) {
        int c = tid + rep * 256;
        float e = (tok != 0) ? emb[(size_t)tok * DMODEL + c] : 0.f;
        int j = c >> 1;
        float freq = __expf(-(float)(2 * j) * (9.210340371976184f / 512.f));
        float ang = (float)t * freq;
        float pe = (c & 1) ? cosf(ang) : sinf(ang);
        xb[(size_t)row * DMODEL + c] = f2bf(e + pe);
    }
}

// ---------------- residual add + LayerNorm, wave-per-row ----------------
// y = LN(t[0..ACTE) + t[ACTE..2*ACTE) + bf16(xb));  writes xb (bf16) or xout (fp32).
__global__ __launch_bounds__(256) void add_ln2(
    const float* __restrict__ t, unsigned short* __restrict__ xb,
    float* __restrict__ xout)
{
    const int lane = threadIdx.x & 63;
    const int row = blockIdx.x * 4 + (threadIdx.x >> 6);
    const size_t idx = (size_t)row * DMODEL + lane * 8;
    float4v t0 = *(const float4v*)(t + idx);
    float4v t1 = *(const float4v*)(t + idx + 4);
    float4v u0 = *(const float4v*)(t + ACTE + idx);
    float4v u1 = *(const float4v*)(t + ACTE + idx + 4);
    bf16x8 rb = *(const bf16x8*)(xb + idx);
    float v[8];
#pragma unroll
    for (int k = 0; k < 4; ++k) {
        v[k] = t0[k] + u0[k] + (float)rb[k];
        v[4 + k] = t1[k] + u1[k] + (float)rb[4 + k];
    }
    float s = 0.f, sq = 0.f;
#pragma unroll
    for (int k = 0; k < 8; ++k) { s += v[k]; sq += v[k] * v[k]; }
#pragma unroll
    for (int o = 1; o < 64; o <<= 1) { s += __shfl_xor(s, o); sq += __shfl_xor(sq, o); }
    float mu = s * (1.f / 512.f);
    float var = sq * (1.f / 512.f) - mu * mu;
    float rstd = rsqrtf(var + 1e-5f);
    if (xout) {
        float4v y0, y1;
#pragma unroll
        for (int k = 0; k < 4; ++k) { y0[k] = (v[k] - mu) * rstd; y1[k] = (v[4 + k] - mu) * rstd; }
        *(float4v*)(xout + idx) = y0;
        *(float4v*)(xout + idx + 4) = y1;
    } else {
        short8v w;
#pragma unroll
        for (int k = 0; k < 8; ++k) w[k] = (short)f2bf((v[k] - mu) * rstd);
        *(short8v*)(xb + idx) = w;
    }
}

// ---------------- bf16 GEMM: C[M,N] = A[M,K] * Bt[N,K]^T ----------------
// 128x128 tile, BK=32, 2x2 waves, 4x4 MFMA 16x16x32 per wave.
// LDS XOR-swizzled 16B chunks -> conflict-free ds_read_b128 fragment reads.
// EPI: 0 fp32 (+SPLITK partials); 1 relu->bf16; 2 head-scatter, Q (which==0)
// pre-scaled by 0.125 (exact in bf16); 3 all-layer KV scatter.
template <int EPI, int SPLITK = 1>
__global__ __launch_bounds__(256) void gemm_bt(
    const unsigned short* __restrict__ A,
    const unsigned short* __restrict__ Bt,
    float* __restrict__ Cf,
    unsigned short* __restrict__ Cb,
    int M, int N, int K)
{
    __shared__ __attribute__((aligned(16))) short As[128 * 32];
    __shared__ __attribute__((aligned(16))) short Bs[128 * 32];
    const int tid = threadIdx.x;
    const int lane = tid & 63, wv = tid >> 6;
    const int quad = lane >> 4, l15 = lane & 15;
    const int m0 = blockIdx.x * 128, n0 = blockIdx.y * 128;
    const int wm = wv & 1, wn = wv >> 1;

    float4v acc[4][4];
#pragma unroll
    for (int i = 0; i < 4; ++i)
#pragma unroll
        for (int j = 0; j < 4; ++j) acc[i][j] = (float4v){0.f, 0.f, 0.f, 0.f};

    const int Kc = K / SPLITK;
    const int kbeg = (SPLITK > 1) ? (int)blockIdx.z * Kc : 0;
    for (int k0 = kbeg; k0 < kbeg + Kc; k0 += 32) {
#pragma unroll
        for (int i = 0; i < 2; ++i) {
            const int inst = wv * 2 + i;                  // 0..7, 1KB each
            const int row = inst * 16 + (lane >> 2);      // tile row this lane fills
            const int cb = (lane & 3) ^ ((row >> 1) & 3); // swizzled 16B chunk
            gl_lds16(A + (size_t)(m0 + row) * K + k0 + cb * 8, (char*)As + inst * 1024);
            gl_lds16(Bt + (size_t)(n0 + row) * K + k0 + cb * 8, (char*)Bs + inst * 1024);
        }
        __syncthreads();
        bf16x8 a[4], b[4];
#pragma unroll
        for (int i = 0; i < 4; ++i) {
            const int r = wm * 64 + i * 16 + l15;
            const int st = quad ^ ((r >> 1) & 3);
            a[i] = *(const bf16x8*)&As[r * 32 + st * 8];
        }
#pragma unroll
        for (int j = 0; j < 4; ++j) {
            const int r = wn * 64 + j * 16 + l15;
            const int st = quad ^ ((r >> 1) & 3);
            b[j] = *(const bf16x8*)&Bs[r * 32 + st * 8];
        }
#pragma unroll
        for (int i = 0; i < 4; ++i)
#pragma unroll
            for (int j = 0; j < 4; ++j)
                acc[i][j] = __builtin_amdgcn_mfma_f32_16x16x32_bf16(a[i], b[j], acc[i][j], 0, 0, 0);
        __syncthreads();
    }

    const size_t zoff = (SPLITK > 1) ? (size_t)blockIdx.z * ACTE : 0;
#pragma unroll
    for (int i = 0; i < 4; ++i) {
        const int row_base = m0 + wm * 64 + i * 16 + quad * 4;
#pragma unroll
        for (int j = 0; j < 4; ++j) {
            const int col = n0 + wn * 64 + j * 16 + l15;
#pragma unroll
            for (int r = 0; r < 4; ++r) {
                const int row = row_base + r;
                const float v = acc[i][j][r];
                if (EPI == 0) {
                    Cf[zoff + (size_t)row * N + col] = v;
                } else if (EPI == 1) {
                    Cb[(size_t)row * N + col] = f2bf(fmaxf(v, 0.f));
                } else if (EPI == 2) {
                    const int which = col >> 9;
                    const float sc = (which == 0) ? 0.125f : 1.f;  // pre-scale Q
                    const int b_ = row >> 10, t = row & (TT - 1);
                    const int h = (col >> 6) & 7, d = col & 63;
                    Cb[(size_t)which * ACTE + (((size_t)(b_ * NH + h)) * TT + t) * DHEAD + d] = f2bf(v * sc);
                } else {
                    const int layer = col >> 10, which = (col >> 9) & 1;
                    const int b_ = row >> 10, t = row & (TT - 1);
                    const int h = (col >> 6) & 7, d = col & 63;
                    Cb[(size_t)(layer * 2 + which) * ACTE +
                       (((size_t)(b_ * NH + h)) * TT + t) * DHEAD + d] = f2bf(v);
                }
            }
        }
    }
}

// ---------------- flash attention ----------------
// Grid (8, B*H). Two q-tiles per block sharing staged KV:
//   causal: (p, 15-p) constant 17 tile-units; cross: (p, p+8).
// Double-buffered KV staging (loads for tile k+1 issued before compute on k),
// independent per-chain Pl/alpha buffers (ILP across the two q-chains),
// pad/causal mask via ballot bitmask (no per-element LDS reads).
// Q is PRE-SCALED by 0.125 in the producing GEMM epilogue.
template <bool CAUSAL>
__global__ __launch_bounds__(256) void attn_kernel(
    const unsigned short* __restrict__ Q,
    const unsigned short* __restrict__ Kb,
    const unsigned short* __restrict__ Vb,
    const int* __restrict__ tokens,   // [B,1024]; token==0 => masked key
    unsigned short* __restrict__ ctx) // [B,T,512] bf16
{
    __shared__ __attribute__((aligned(16))) short Ks[2][64 * 64];   // [key][d] swizzled
    __shared__ __attribute__((aligned(16))) short Vt[2][64 * 64];   // [d][key] swizzled
    __shared__ __attribute__((aligned(16))) short Pl[2][4][16 * 72];
    __shared__ __attribute__((aligned(16))) float alph[2][4][16];

    const int tid = threadIdx.x, lane = tid & 63, wv = tid >> 6;
    const int quad = lane >> 4, l15 = lane & 15;
    const int p = blockIdx.x;
    const int bh = blockIdx.y;
    const int b = bh >> 3, h = bh & 7;
    const size_t kvbase = (size_t)bh * TT * DHEAD;

    const int qt0 = p;
    const int qt1 = CAUSAL ? (15 - p) : (p + 8);
    const int qg0 = qt0 * 64 + wv * 16 + l15;
    const int qg1 = qt1 * 64 + wv * 16 + l15;

    const bf16x8 qa0 = *(const bf16x8*)&Q[kvbase + (size_t)qg0 * DHEAD + quad * 8];
    const bf16x8 qa1 = *(const bf16x8*)&Q[kvbase + (size_t)qg0 * DHEAD + 32 + quad * 8];
    const bf16x8 qb0 = *(const bf16x8*)&Q[kvbase + (size_t)qg1 * DHEAD + quad * 8];
    const bf16x8 qb1 = *(const bf16x8*)&Q[kvbase + (size_t)qg1 * DHEAD + 32 + quad * 8];

    float4v O0[4], O1[4];
#pragma unroll
    for (int j = 0; j < 4; ++j) { O0[j] = (float4v){0.f,0.f,0.f,0.f}; O1[j] = (float4v){0.f,0.f,0.f,0.f}; }
    float m0_ = -INFINITY, l0_ = 0.f, m1_ = -INFINITY, l1_ = 0.f;

    // staging helpers
    const int key0 = (lane & 31) * 2;            // V-transpose lane roles
    const int d0 = (lane >> 5) * 8 + wv * 16;
    auto stageK = [&](int kt, int buf) {
#pragma unroll
        for (int i = 0; i < 2; ++i) {
            const int inst = wv * 2 + i;
            const int row = inst * 8 + (lane >> 3);
            const int cb = (lane & 7) ^ (row & 7);
            gl_lds16(Kb + kvbase + (size_t)(kt * 64 + row) * DHEAD + cb * 8,
                     (char*)Ks[buf] + inst * 1024);
        }
    };
    auto loadV = [&](int kt, short8v& r0, short8v& r1) {
        const unsigned short* vp = Vb + kvbase + (size_t)(kt * 64 + key0) * DHEAD + d0;
        r0 = *(const short8v*)vp;
        r1 = *(const short8v*)(vp + DHEAD);
    };
    auto writeV = [&](int buf, const short8v& r0, const short8v& r1) {
        const int kc = key0 >> 3, ko = key0 & 7;
#pragma unroll
        for (int j = 0; j < 8; ++j) {
            const int d = d0 + j;
            unsigned pk = (unsigned)(unsigned short)r0[j] |
                          ((unsigned)(unsigned short)r1[j] << 16);
            *(unsigned*)&Vt[buf][d * 64 + ((kc ^ (d & 7)) << 3) + ko] = pk;
        }
    };

    int kt = 0;
    auto process = [&](int ch, const bf16x8& qf0, const bf16x8& qf1, int qg,
                       float& m, float& l, float4v* O,
                       int cur, unsigned long long kbits) {
        // S^T = K * Q^T : D[key][q]   (Q pre-scaled by 1/8)
        float4v st[4];
#pragma unroll
        for (int i = 0; i < 4; ++i) {
            const int row = i * 16 + l15;
            const int s0 = quad ^ (row & 7);
            const int s1 = (4 + quad) ^ (row & 7);
            bf16x8 kf0 = *(const bf16x8*)&Ks[cur][row * 64 + s0 * 8];
            bf16x8 kf1 = *(const bf16x8*)&Ks[cur][row * 64 + s1 * 8];
            float4v z = (float4v){0.f, 0.f, 0.f, 0.f};
            z = __builtin_amdgcn_mfma_f32_16x16x32_bf16(kf0, qf0, z, 0, 0, 0);
            z = __builtin_amdgcn_mfma_f32_16x16x32_bf16(kf1, qf1, z, 0, 0, 0);
            st[i] = z;
        }
        // combined mask bits: pad keys + (diagonal tile only) causal
        unsigned long long mask = kbits;
        if (CAUSAL && kt * 64 + 63 > qg) {
            const int qcol = qg & 63;
            mask |= (qcol == 63) ? 0ull : (~0ull << (qcol + 1));
        }
        float sv[16], smax = -INFINITY;
#pragma unroll
        for (int i = 0; i < 4; ++i)
#pragma unroll
            for (int r = 0; r < 4; ++r) {
                const int kl = i * 16 + quad * 4 + r;
                float s = ((mask >> kl) & 1ull) ? -1e9f : st[i][r];
                sv[i * 4 + r] = s;
                smax = fmaxf(smax, s);
            }
        smax = fmaxf(smax, __shfl_xor(smax, 16));
        smax = fmaxf(smax, __shfl_xor(smax, 32));
        const float mnew = fmaxf(m, smax);
        const float alpha = __expf(m - mnew);
        float tsum = 0.f;
#pragma unroll
        for (int i = 0; i < 16; ++i) { float pv = __expf(sv[i] - mnew); sv[i] = pv; tsum += pv; }
        tsum += __shfl_xor(tsum, 16);
        tsum += __shfl_xor(tsum, 32);
        l = l * alpha + tsum;
        m = mnew;
#pragma unroll
        for (int i = 0; i < 4; ++i) {
            short4v pw;
#pragma unroll
            for (int r = 0; r < 4; ++r) pw[r] = (short)f2bf(sv[i * 4 + r]);
            *(short4v*)&Pl[ch][wv][l15 * 72 + i * 16 + quad * 4] = pw;
        }
        if (lane < 16) alph[ch][wv][lane] = alpha;
        const float4v aw = *(const float4v*)&alph[ch][wv][quad * 4];
        const bf16x8 p0 = *(const bf16x8*)&Pl[ch][wv][l15 * 72 + quad * 8];
        const bf16x8 p1 = *(const bf16x8*)&Pl[ch][wv][l15 * 72 + 32 + quad * 8];
#pragma unroll
        for (int j = 0; j < 4; ++j) {
            const int row = j * 16 + l15;
            const int s0 = quad ^ (row & 7);
            const int s1 = (4 + quad) ^ (row & 7);
            bf16x8 v0f = *(const bf16x8*)&Vt[cur][row * 64 + s0 * 8];
            bf16x8 v1f = *(const bf16x8*)&Vt[cur][row * 64 + s1 * 8];
            float4v o = O[j] * aw;
            o = __builtin_amdgcn_mfma_f32_16x16x32_bf16(p0, v0f, o, 0, 0, 0);
            o = __builtin_amdgcn_mfma_f32_16x16x32_bf16(p1, v1f, o, 0, 0, 0);
            O[j] = o;
        }
    };

    const int nkt = CAUSAL ? (qt1 + 1) : 16;

    // prologue: stage tile 0 into buffer 0
    stageK(0, 0);
    {
        short8v v0a, v0b;
        loadV(0, v0a, v0b);
        writeV(0, v0a, v0b);
    }
    int tok_cur = tokens[(size_t)b * TT + lane];
    __syncthreads();

    short8v vn0, vn1;
    int tok_next = 0;
    for (kt = 0; kt < nkt; ++kt) {
        const int cur = kt & 1, nxt = cur ^ 1;
        const bool more = (kt + 1 < nkt);
        if (more) {
            stageK(kt + 1, nxt);                       // async DMA into other buffer
            loadV(kt + 1, vn0, vn1);                   // V prefetch into regs
            tok_next = tokens[(size_t)b * TT + (kt + 1) * 64 + lane];
        }
        const unsigned long long kbits = __ballot(tok_cur == 0);

        if (!CAUSAL || kt <= qt0) process(0, qa0, qa1, qg0, m0_, l0_, O0, cur, kbits);
        process(1, qb0, qb1, qg1, m1_, l1_, O1, cur, kbits);

        if (more) {
            writeV(nxt, vn0, vn1);                     // V regs -> LDS (loads have landed)
            tok_cur = tok_next;
        }
        __syncthreads();                                // drains K DMA (already landed)
    }

    auto finalize = [&](int ch, float l, float4v* O, int qt) {
        if (lane < 16) alph[ch][wv][lane] = l;
        const float4v lw = *(const float4v*)&alph[ch][wv][quad * 4];
#pragma unroll
        for (int j = 0; j < 4; ++j)
#pragma unroll
            for (int r = 0; r < 4; ++r) {
                const int qrow = qt * 64 + wv * 16 + quad * 4 + r;
                ctx[((size_t)b * TT + qrow) * DMODEL + h * DHEAD + j * 16 + l15] =
                    f2bf(O[j][r] / lw[r]);
            }
    };
    finalize(0, l0_, O0, qt0);
    finalize(1, l1_, O1, qt1);
}

// ---------------- host ----------------
extern "C" void kernel_launch(void* const* d_in, const int* in_sizes, int n_in,
                              void* d_out, int out_size, void* d_ws, size_t ws_size,
                              hipStream_t stream)
{
    const int* dec = (const int*)d_in[0];
    const int* enc = (const int*)d_in[1];
    const float* enc_out = (const float*)d_in[2];
    const float* emb = (const float*)d_in[3];
    const float* Wq_s = (const float*)d_in[4];
    const float* Wk_s = (const float*)d_in[5];
    const float* Wv_s = (const float*)d_in[6];
    const float* Wo_s = (const float*)d_in[7];
    const float* Wq_c = (const float*)d_in[8];
    const float* Wk_c = (const float*)d_in[9];
    const float* Wv_c = (const float*)d_in[10];
    const float* Wo_c = (const float*)d_in[11];
    const float* W1 = (const float*)d_in[12];
    const float* W2 = (const float*)d_in[13];
    float* out = (float*)d_out;

    char* p = (char*)d_ws;
    auto carve = [&](size_t bytes) -> char* {
        char* r = p;
        p += (bytes + 255) & ~(size_t)255;
        return r;
    };
    unsigned short* xb   = (unsigned short*)carve(ACTE * 2);
    float* tmp1          = (float*)carve(2 * ACTE * 4);           // 2 split-K partial slices
    unsigned short* qkvb = (unsigned short*)carve(3 * ACTE * 2);  // Q|K|V contiguous
    unsigned short* ctxb = (unsigned short*)carve(ACTE * 2);
    unsigned short* encb = (unsigned short*)carve(ACTE * 2);
    unsigned short* h1   = (unsigned short*)carve((size_t)NTOK * DFF * 2);
    unsigned short* wqkvT = (unsigned short*)carve((size_t)NLAYER * 1536 * 512 * 2);
    unsigned short* woT   = (unsigned short*)carve((size_t)NLAYER * 512 * 512 * 2);
    unsigned short* wqcT  = (unsigned short*)carve((size_t)NLAYER * 512 * 512 * 2);
    unsigned short* wkvcT = (unsigned short*)carve((size_t)NLAYER * 1024 * 512 * 2);
    unsigned short* wocT  = (unsigned short*)carve((size_t)NLAYER * 512 * 512 * 2);
    unsigned short* w1T   = (unsigned short*)carve((size_t)NLAYER * 2048 * 512 * 2);
    unsigned short* w2T   = (unsigned short*)carve((size_t)NLAYER * 512 * 2048 * 2);
    const size_t used = (size_t)(p - (char*)d_ws);
    const bool pre = (used + 12 * ACTE * 2 + 256) <= ws_size;  // all-layer cross K/V cache
    unsigned short* KVc = pre ? (unsigned short*)carve(12 * ACTE * 2) : nullptr;

    // weight prep: 8 small transposes merged into one dispatch
    Tr8Args ta;
    ta.src[0] = Wq_s; ta.dst[0] = wqkvT; ta.dstL[0] = 1536 * 512; ta.rowOff[0] = 0;
    ta.src[1] = Wk_s; ta.dst[1] = wqkvT; ta.dstL[1] = 1536 * 512; ta.rowOff[1] = 512;
    ta.src[2] = Wv_s; ta.dst[2] = wqkvT; ta.dstL[2] = 1536 * 512; ta.rowOff[2] = 1024;
    ta.src[3] = Wo_s; ta.dst[3] = woT;   ta.dstL[3] = 512 * 512;  ta.rowOff[3] = 0;
    ta.src[4] = Wq_c; ta.dst[4] = wqcT;  ta.dstL[4] = 512 * 512;  ta.rowOff[4] = 0;
    ta.src[5] = Wk_c; ta.dst[5] = wkvcT; ta.dstL[5] = 1024 * 512; ta.rowOff[5] = 0;
    ta.src[6] = Wv_c; ta.dst[6] = wkvcT; ta.dstL[6] = 1024 * 512; ta.rowOff[6] = 512;
    ta.src[7] = Wo_c; ta.dst[7] = wocT;  ta.dstL[7] = 512 * 512;  ta.rowOff[7] = 0;
    transpose8_kernel<<<dim3(8, 8, 48), 256, 0, stream>>>(ta);
    transpose_conv_kernel<<<dim3(8, 32, NLAYER), 256, 0, stream>>>(W1, w1T, 512, 2048, (size_t)2048 * 512, 0);
    transpose_conv_kernel<<<dim3(32, 8, NLAYER), 256, 0, stream>>>(W2, w2T, 2048, 512, (size_t)512 * 2048, 0);
    conv_bf16_kernel<<<(int)(ACTE / 1024), 256, 0, stream>>>(enc_out, encb);
    embed_kernel<<<NTOK, 256, 0, stream>>>(dec, emb, xb);

    // cross K/V for ALL layers in one big GEMM (enc side is layer-invariant)
    if (pre)
        gemm_bt<3><<<dim3(64, 48), 256, 0, stream>>>(encb, wkvcT, nullptr, KVc, NTOK, 6144, 512);

    for (int lyr = 0; lyr < NLAYER; ++lyr) {
        const unsigned short* wqkv = wqkvT + (size_t)lyr * 1536 * 512;
        const unsigned short* wo   = woT + (size_t)lyr * 512 * 512;
        const unsigned short* wqc  = wqcT + (size_t)lyr * 512 * 512;
        const unsigned short* wkvc = wkvcT + (size_t)lyr * 1024 * 512;
        const unsigned short* woc  = wocT + (size_t)lyr * 512 * 512;
        const unsigned short* w1   = w1T + (size_t)lyr * 2048 * 512;
        const unsigned short* w2   = w2T + (size_t)lyr * 512 * 2048;

        // ---- self attention ----
        gemm_bt<2><<<dim3(64, 12), 256, 0, stream>>>(xb, wqkv, nullptr, qkvb, NTOK, 1536, 512);
        attn_kernel<true><<<dim3(8, BB * NH), 256, 0, stream>>>(
            qkvb, qkvb + ACTE, qkvb + 2 * ACTE, dec, ctxb);
        gemm_bt<0, 2><<<dim3(64, 4, 2), 256, 0, stream>>>(ctxb, wo, tmp1, nullptr, NTOK, 512, 512);
        add_ln2<<<NTOK / 4, 256, 0, stream>>>(tmp1, xb, nullptr);

        // ---- cross attention ----
        gemm_bt<2><<<dim3(64, 4), 256, 0, stream>>>(xb, wqc, nullptr, qkvb, NTOK, 512, 512);
        const unsigned short* Kc;
        if (pre) {
            Kc = KVc + (size_t)lyr * 2 * ACTE;
        } else {
            gemm_bt<2><<<dim3(64, 8), 256, 0, stream>>>(encb, wkvc, nullptr, qkvb + ACTE, NTOK, 1024, 512);
            Kc = qkvb + ACTE;
        }
        attn_kernel<false><<<dim3(8, BB * NH), 256, 0, stream>>>(
            qkvb, Kc, Kc + ACTE, enc, ctxb);
        gemm_bt<0, 2><<<dim3(64, 4, 2), 256, 0, stream>>>(ctxb, woc, tmp1, nullptr, NTOK, 512, 512);
        add_ln2<<<NTOK / 4, 256, 0, stream>>>(tmp1, xb, nullptr);

        // ---- FFN ----
        gemm_bt<1><<<dim3(64, 16), 256, 0, stream>>>(xb, w1, nullptr, h1, NTOK, 2048, 512);
        gemm_bt<0, 2><<<dim3(64, 4, 2), 256, 0, stream>>>(h1, w2, tmp1, nullptr, NTOK, 512, 2048);
        add_ln2<<<NTOK / 4, 256, 0, stream>>>(tmp1, xb, (lyr == NLAYER - 1) ? out : nullptr);
    }
    (void)in_sizes; (void)n_in; (void)out_size;
}

// Round 5
// 1647.580 us; speedup vs baseline: 1.3989x; 1.0249x over previous
//
#include <hip/hip_runtime.h>
#include <hip/hip_bf16.h>

// ---------------- problem constants ----------------
#define DMODEL 512
#define NH     8
#define DHEAD  64
#define DFF    2048
#define NLAYER 6
#define BB     8
#define TT     1024
#define NTOK   (BB*TT)                 // 8192 rows
#define ACTE   ((size_t)NTOK*DMODEL)   // 4,194,304 elements

// Q pre-scale: (1/sqrt(64)) * log2(e)  -> scores arrive in exp2 domain
#define QSCALE 0.18033688011112042f

typedef __bf16  bf16x8  __attribute__((ext_vector_type(8)));
typedef float   float4v __attribute__((ext_vector_type(4)));
typedef short   short4v __attribute__((ext_vector_type(4)));
typedef short   short8v __attribute__((ext_vector_type(8)));

__device__ __forceinline__ unsigned short f2bf(float f) {
    __hip_bfloat16 h = __float2bfloat16(f);
    return *reinterpret_cast<unsigned short*>(&h);
}

// raw v_exp_f32 (2^x). s_nop 0 covers the VALU-trans->VALU hazard.
__device__ __forceinline__ float exp2_fast(float x) {
    float r;
    asm("v_exp_f32 %0, %1\n\ts_nop 0" : "=v"(r) : "v"(x));
    return r;
}

// async global->LDS, 16B/lane. LDS base wave-uniform; HW adds lane*16.
// Global address is PER-LANE -> used to write a swizzled LDS layout for free.
__device__ __forceinline__ void gl_lds16(const void* g, void* l) {
    __builtin_amdgcn_global_load_lds((const __attribute__((address_space(1))) void*)g,
                                     (__attribute__((address_space(3))) void*)l, 16, 0, 0);
}

// ---------------- merged small-weight transpose (8 types x 6 layers) ----------------
struct Tr8Args {
    const float* src[8];
    unsigned short* dst[8];
    int dstL[8];    // per-layer dst stride (elements)
    int rowOff[8];
};
__global__ __launch_bounds__(256) void transpose8_kernel(Tr8Args a)
{
    __shared__ float tile[64][65];
    const int type = blockIdx.z / 6, lyr = blockIdx.z % 6;
    const float* src = a.src[type] + (size_t)lyr * 512 * 512;
    unsigned short* dst = a.dst[type] + (size_t)lyr * a.dstL[type];
    const int rowOff = a.rowOff[type];
    const int k0 = blockIdx.x * 64, n0 = blockIdx.y * 64;
    const int tid = threadIdx.x;
#pragma unroll
    for (int rep = 0; rep < 16; ++rep) {
        int idx = rep * 256 + tid;
        int r = idx >> 6, c = idx & 63;
        tile[r][c] = src[(size_t)(k0 + r) * 512 + n0 + c];
    }
    __syncthreads();
#pragma unroll
    for (int rep = 0; rep < 16; ++rep) {
        int idx = rep * 256 + tid;
        int r = idx >> 6, c = idx & 63;
        dst[(size_t)(rowOff + n0 + r) * 512 + k0 + c] = f2bf(tile[c][r]);
    }
}

// ---------------- generic transpose (W1/W2) ----------------
__global__ __launch_bounds__(256) void transpose_conv_kernel(
    const float* __restrict__ W, unsigned short* __restrict__ Wt, int K, int N,
    size_t dstL, int rowOff)
{
    __shared__ float tile[64][65];
    const float* src = W + (size_t)blockIdx.z * K * N;
    unsigned short* dst = Wt + (size_t)blockIdx.z * dstL;
    const int k0 = blockIdx.x * 64, n0 = blockIdx.y * 64;
    const int tid = threadIdx.x;
#pragma unroll
    for (int rep = 0; rep < 16; ++rep) {
        int idx = rep * 256 + tid;
        int r = idx >> 6, c = idx & 63;
        tile[r][c] = src[(size_t)(k0 + r) * N + n0 + c];
    }
    __syncthreads();
#pragma unroll
    for (int rep = 0; rep < 16; ++rep) {
        int idx = rep * 256 + tid;
        int r = idx >> 6, c = idx & 63;
        dst[(size_t)(rowOff + n0 + r) * K + k0 + c] = f2bf(tile[c][r]);
    }
}

// ---------------- fp32 -> bf16 convert ----------------
__global__ __launch_bounds__(256) void conv_bf16_kernel(
    const float* __restrict__ in, unsigned short* __restrict__ o)
{
    int i = (blockIdx.x * 256 + threadIdx.x) * 4;
    float4v v = *(const float4v*)(in + i);
    short4v w;
    w[0] = (short)f2bf(v[0]); w[1] = (short)f2bf(v[1]);
    w[2] = (short)f2bf(v[2]); w[3] = (short)f2bf(v[3]);
    *(short4v*)(o + i) = w;
}

// ---------------- embedding + sinusoidal PE (bf16 out only) ----------------
__global__ __launch_bounds__(256) void embed_kernel(
    const int* __restrict__ dec, const float* __restrict__ emb,
    unsigned short* __restrict__ xb)
{
    const int row = blockIdx.x;            // 0..8191
    const int t = row & (TT - 1);
    const int tid = threadIdx.x;
    const int tok = dec[row];
#pragma unroll
    for (int rep = 0; rep < 2; ++rep) {
        int c = tid + rep * 256;
        float e = (tok != 0) ? emb[(size_t)tok * DMODEL + c] : 0.f;
        int j = c >> 1;
        float freq = __expf(-(float)(2 * j) * (9.210340371976184f / 512.f));
        float ang = (float)t * freq;
        float pe = (c & 1) ? cosf(ang) : sinf(ang);
        xb[(size_t)row * DMODEL + c] = f2bf(e + pe);
    }
}

// ---------------- residual add + LayerNorm, wave-per-row ----------------
// y = LN(t[0..ACTE) + t[ACTE..2*ACTE) + bf16(xb));  writes xb (bf16) or xout (fp32).
__global__ __launch_bounds__(256) void add_ln2(
    const float* __restrict__ t, unsigned short* __restrict__ xb,
    float* __restrict__ xout)
{
    const int lane = threadIdx.x & 63;
    const int row = blockIdx.x * 4 + (threadIdx.x >> 6);
    const size_t idx = (size_t)row * DMODEL + lane * 8;
    float4v t0 = *(const float4v*)(t + idx);
    float4v t1 = *(const float4v*)(t + idx + 4);
    float4v u0 = *(const float4v*)(t + ACTE + idx);
    float4v u1 = *(const float4v*)(t + ACTE + idx + 4);
    bf16x8 rb = *(const bf16x8*)(xb + idx);
    float v[8];
#pragma unroll
    for (int k = 0; k < 4; ++k) {
        v[k] = t0[k] + u0[k] + (float)rb[k];
        v[4 + k] = t1[k] + u1[k] + (float)rb[4 + k];
    }
    float s = 0.f, sq = 0.f;
#pragma unroll
    for (int k = 0; k < 8; ++k) { s += v[k]; sq += v[k] * v[k]; }
#pragma unroll
    for (int o = 1; o < 64; o <<= 1) { s += __shfl_xor(s, o); sq += __shfl_xor(sq, o); }
    float mu = s * (1.f / 512.f);
    float var = sq * (1.f / 512.f) - mu * mu;
    float rstd = rsqrtf(var + 1e-5f);
    if (xout) {
        float4v y0, y1;
#pragma unroll
        for (int k = 0; k < 4; ++k) { y0[k] = (v[k] - mu) * rstd; y1[k] = (v[4 + k] - mu) * rstd; }
        *(float4v*)(xout + idx) = y0;
        *(float4v*)(xout + idx + 4) = y1;
    } else {
        short8v w;
#pragma unroll
        for (int k = 0; k < 8; ++k) w[k] = (short)f2bf((v[k] - mu) * rstd);
        *(short8v*)(xb + idx) = w;
    }
}

// ---------------- bf16 GEMM: C[M,N] = A[M,K] * Bt[N,K]^T ----------------
// 128x128 tile, BK=32, 2x2 waves, 4x4 MFMA 16x16x32 per wave.
// LDS XOR-swizzled 16B chunks -> conflict-free ds_read_b128 fragment reads.
// EPI: 0 fp32 (+SPLITK partials); 1 relu->bf16; 2 head-scatter, Q (which==0)
// pre-scaled by QSCALE (exp2-domain softmax); 3 all-layer KV scatter.
template <int EPI, int SPLITK = 1>
__global__ __launch_bounds__(256) void gemm_bt(
    const unsigned short* __restrict__ A,
    const unsigned short* __restrict__ Bt,
    float* __restrict__ Cf,
    unsigned short* __restrict__ Cb,
    int M, int N, int K)
{
    __shared__ __attribute__((aligned(16))) short As[128 * 32];
    __shared__ __attribute__((aligned(16))) short Bs[128 * 32];
    const int tid = threadIdx.x;
    const int lane = tid & 63, wv = tid >> 6;
    const int quad = lane >> 4, l15 = lane & 15;
    const int m0 = blockIdx.x * 128, n0 = blockIdx.y * 128;
    const int wm = wv & 1, wn = wv >> 1;

    float4v acc[4][4];
#pragma unroll
    for (int i = 0; i < 4; ++i)
#pragma unroll
        for (int j = 0; j < 4; ++j) acc[i][j] = (float4v){0.f, 0.f, 0.f, 0.f};

    const int Kc = K / SPLITK;
    const int kbeg = (SPLITK > 1) ? (int)blockIdx.z * Kc : 0;
    for (int k0 = kbeg; k0 < kbeg + Kc; k0 += 32) {
#pragma unroll
        for (int i = 0; i < 2; ++i) {
            const int inst = wv * 2 + i;                  // 0..7, 1KB each
            const int row = inst * 16 + (lane >> 2);      // tile row this lane fills
            const int cb = (lane & 3) ^ ((row >> 1) & 3); // swizzled 16B chunk
            gl_lds16(A + (size_t)(m0 + row) * K + k0 + cb * 8, (char*)As + inst * 1024);
            gl_lds16(Bt + (size_t)(n0 + row) * K + k0 + cb * 8, (char*)Bs + inst * 1024);
        }
        __syncthreads();
        bf16x8 a[4], b[4];
#pragma unroll
        for (int i = 0; i < 4; ++i) {
            const int r = wm * 64 + i * 16 + l15;
            const int st = quad ^ ((r >> 1) & 3);
            a[i] = *(const bf16x8*)&As[r * 32 + st * 8];
        }
#pragma unroll
        for (int j = 0; j < 4; ++j) {
            const int r = wn * 64 + j * 16 + l15;
            const int st = quad ^ ((r >> 1) & 3);
            b[j] = *(const bf16x8*)&Bs[r * 32 + st * 8];
        }
#pragma unroll
        for (int i = 0; i < 4; ++i)
#pragma unroll
            for (int j = 0; j < 4; ++j)
                acc[i][j] = __builtin_amdgcn_mfma_f32_16x16x32_bf16(a[i], b[j], acc[i][j], 0, 0, 0);
        __syncthreads();
    }

    const size_t zoff = (SPLITK > 1) ? (size_t)blockIdx.z * ACTE : 0;
#pragma unroll
    for (int i = 0; i < 4; ++i) {
        const int row_base = m0 + wm * 64 + i * 16 + quad * 4;
#pragma unroll
        for (int j = 0; j < 4; ++j) {
            const int col = n0 + wn * 64 + j * 16 + l15;
#pragma unroll
            for (int r = 0; r < 4; ++r) {
                const int row = row_base + r;
                const float v = acc[i][j][r];
                if (EPI == 0) {
                    Cf[zoff + (size_t)row * N + col] = v;
                } else if (EPI == 1) {
                    Cb[(size_t)row * N + col] = f2bf(fmaxf(v, 0.f));
                } else if (EPI == 2) {
                    const int which = col >> 9;
                    const float sc = (which == 0) ? QSCALE : 1.f;  // pre-scale Q
                    const int b_ = row >> 10, t = row & (TT - 1);
                    const int h = (col >> 6) & 7, d = col & 63;
                    Cb[(size_t)which * ACTE + (((size_t)(b_ * NH + h)) * TT + t) * DHEAD + d] = f2bf(v * sc);
                } else {
                    const int layer = col >> 10, which = (col >> 9) & 1;
                    const int b_ = row >> 10, t = row & (TT - 1);
                    const int h = (col >> 6) & 7, d = col & 63;
                    Cb[(size_t)(layer * 2 + which) * ACTE +
                       (((size_t)(b_ * NH + h)) * TT + t) * DHEAD + d] = f2bf(v);
                }
            }
        }
    }
}

// ---------------- flash attention ----------------
// Grid (8, B*H). Two q-tiles per block sharing staged KV:
//   causal: (p, 15-p) constant 17 tile-units; cross: (p, p+8).
// Double-buffered KV staging; K/V fragments hoisted to registers ONCE per tile
// and shared by both q-chains; pad/causal mask via ballot bitmask; softmax in
// exp2 domain (Q pre-scaled by QSCALE in the producing GEMM).
template <bool CAUSAL>
__global__ __launch_bounds__(256, 2) void attn_kernel(
    const unsigned short* __restrict__ Q,
    const unsigned short* __restrict__ Kb,
    const unsigned short* __restrict__ Vb,
    const int* __restrict__ tokens,   // [B,1024]; token==0 => masked key
    unsigned short* __restrict__ ctx) // [B,T,512] bf16
{
    __shared__ __attribute__((aligned(16))) short Ks[2][64 * 64];   // [key][d] swizzled
    __shared__ __attribute__((aligned(16))) short Vt[2][64 * 64];   // [d][key] swizzled
    __shared__ __attribute__((aligned(16))) short Pl[2][4][16 * 72];
    __shared__ __attribute__((aligned(16))) float alph[2][4][16];

    const int tid = threadIdx.x, lane = tid & 63, wv = tid >> 6;
    const int quad = lane >> 4, l15 = lane & 15;
    const int p = blockIdx.x;
    const int bh = blockIdx.y;
    const int b = bh >> 3, h = bh & 7;
    const size_t kvbase = (size_t)bh * TT * DHEAD;

    const int qt0 = p;
    const int qt1 = CAUSAL ? (15 - p) : (p + 8);
    const int qg0 = qt0 * 64 + wv * 16 + l15;
    const int qg1 = qt1 * 64 + wv * 16 + l15;

    const bf16x8 qa0 = *(const bf16x8*)&Q[kvbase + (size_t)qg0 * DHEAD + quad * 8];
    const bf16x8 qa1 = *(const bf16x8*)&Q[kvbase + (size_t)qg0 * DHEAD + 32 + quad * 8];
    const bf16x8 qb0 = *(const bf16x8*)&Q[kvbase + (size_t)qg1 * DHEAD + quad * 8];
    const bf16x8 qb1 = *(const bf16x8*)&Q[kvbase + (size_t)qg1 * DHEAD + 32 + quad * 8];

    float4v O0[4], O1[4];
#pragma unroll
    for (int j = 0; j < 4; ++j) { O0[j] = (float4v){0.f,0.f,0.f,0.f}; O1[j] = (float4v){0.f,0.f,0.f,0.f}; }
    float m0_ = -INFINITY, l0_ = 0.f, m1_ = -INFINITY, l1_ = 0.f;

    // staging helpers
    const int key0 = (lane & 31) * 2;            // V-transpose lane roles
    const int d0 = (lane >> 5) * 8 + wv * 16;
    auto stageK = [&](int kt_, int buf) {
#pragma unroll
        for (int i = 0; i < 2; ++i) {
            const int inst = wv * 2 + i;
            const int row = inst * 8 + (lane >> 3);
            const int cb = (lane & 7) ^ (row & 7);
            gl_lds16(Kb + kvbase + (size_t)(kt_ * 64 + row) * DHEAD + cb * 8,
                     (char*)Ks[buf] + inst * 1024);
        }
    };
    auto loadV = [&](int kt_, short8v& r0, short8v& r1) {
        const unsigned short* vp = Vb + kvbase + (size_t)(kt_ * 64 + key0) * DHEAD + d0;
        r0 = *(const short8v*)vp;
        r1 = *(const short8v*)(vp + DHEAD);
    };
    auto writeV = [&](int buf, const short8v& r0, const short8v& r1) {
        const int kc = key0 >> 3, ko = key0 & 7;
#pragma unroll
        for (int j = 0; j < 8; ++j) {
            const int d = d0 + j;
            unsigned pk = (unsigned)(unsigned short)r0[j] |
                          ((unsigned)(unsigned short)r1[j] << 16);
            *(unsigned*)&Vt[buf][d * 64 + ((kc ^ (d & 7)) << 3) + ko] = pk;
        }
    };

    int kt = 0;
    bf16x8 kf[4][2], vf[4][2];  // per-tile fragments, shared by both q-chains

    auto process = [&](int ch, const bf16x8& qf0, const bf16x8& qf1, int qg,
                       float& m, float& l, float4v* O, unsigned long long kbits) {
        // S^T = K * Q^T : D[key][q]   (scores already in exp2 domain)
        float4v st[4];
#pragma unroll
        for (int i = 0; i < 4; ++i) {
            float4v z = (float4v){0.f, 0.f, 0.f, 0.f};
            z = __builtin_amdgcn_mfma_f32_16x16x32_bf16(kf[i][0], qf0, z, 0, 0, 0);
            z = __builtin_amdgcn_mfma_f32_16x16x32_bf16(kf[i][1], qf1, z, 0, 0, 0);
            st[i] = z;
        }
        // combined mask bits: pad keys + (diagonal tile only) causal
        unsigned long long mask = kbits;
        if (CAUSAL && kt * 64 + 63 > qg) {
            const int qcol = qg & 63;
            mask |= (qcol == 63) ? 0ull : (~0ull << (qcol + 1));
        }
        float sv[16], smax = -INFINITY;
#pragma unroll
        for (int i = 0; i < 4; ++i)
#pragma unroll
            for (int r = 0; r < 4; ++r) {
                const int kl = i * 16 + quad * 4 + r;
                float s = ((mask >> kl) & 1ull) ? -1e9f : st[i][r];
                sv[i * 4 + r] = s;
                smax = fmaxf(smax, s);
            }
        smax = fmaxf(smax, __shfl_xor(smax, 16));
        smax = fmaxf(smax, __shfl_xor(smax, 32));
        const float mnew = fmaxf(m, smax);
        const float alpha = exp2_fast(m - mnew);
        float tsum = 0.f;
#pragma unroll
        for (int i = 0; i < 16; ++i) { float pv = exp2_fast(sv[i] - mnew); sv[i] = pv; tsum += pv; }
        tsum += __shfl_xor(tsum, 16);
        tsum += __shfl_xor(tsum, 32);
        l = l * alpha + tsum;
        m = mnew;
#pragma unroll
        for (int i = 0; i < 4; ++i) {
            short4v pw;
#pragma unroll
            for (int r = 0; r < 4; ++r) pw[r] = (short)f2bf(sv[i * 4 + r]);
            *(short4v*)&Pl[ch][wv][l15 * 72 + i * 16 + quad * 4] = pw;
        }
        if (lane < 16) alph[ch][wv][lane] = alpha;
        const float4v aw = *(const float4v*)&alph[ch][wv][quad * 4];
        const bf16x8 p0 = *(const bf16x8*)&Pl[ch][wv][l15 * 72 + quad * 8];
        const bf16x8 p1 = *(const bf16x8*)&Pl[ch][wv][l15 * 72 + 32 + quad * 8];
#pragma unroll
        for (int j = 0; j < 4; ++j) {
            float4v o = O[j] * aw;
            o = __builtin_amdgcn_mfma_f32_16x16x32_bf16(p0, vf[j][0], o, 0, 0, 0);
            o = __builtin_amdgcn_mfma_f32_16x16x32_bf16(p1, vf[j][1], o, 0, 0, 0);
            O[j] = o;
        }
    };

    const int nkt = CAUSAL ? (qt1 + 1) : 16;

    // prologue: stage tile 0 into buffer 0
    stageK(0, 0);
    {
        short8v v0a, v0b;
        loadV(0, v0a, v0b);
        writeV(0, v0a, v0b);
    }
    int tok_cur = tokens[(size_t)b * TT + lane];
    __syncthreads();

    short8v vn0, vn1;
    int tok_next = 0;
    for (kt = 0; kt < nkt; ++kt) {
        const int cur = kt & 1, nxt = cur ^ 1;
        const bool more = (kt + 1 < nkt);
        if (more) {
            stageK(kt + 1, nxt);                       // async DMA into other buffer
            loadV(kt + 1, vn0, vn1);                   // V prefetch into regs
            tok_next = tokens[(size_t)b * TT + (kt + 1) * 64 + lane];
        }
        const unsigned long long kbits = __ballot(tok_cur == 0);

        // hoist K/V fragments once per tile (shared by both chains)
#pragma unroll
        for (int i = 0; i < 4; ++i) {
            const int row = i * 16 + l15;
            const int s0 = quad ^ (row & 7);
            const int s1 = (4 + quad) ^ (row & 7);
            kf[i][0] = *(const bf16x8*)&Ks[cur][row * 64 + s0 * 8];
            kf[i][1] = *(const bf16x8*)&Ks[cur][row * 64 + s1 * 8];
            vf[i][0] = *(const bf16x8*)&Vt[cur][row * 64 + s0 * 8];
            vf[i][1] = *(const bf16x8*)&Vt[cur][row * 64 + s1 * 8];
        }

        if (!CAUSAL || kt <= qt0) process(0, qa0, qa1, qg0, m0_, l0_, O0, kbits);
        process(1, qb0, qb1, qg1, m1_, l1_, O1, kbits);

        if (more) {
            writeV(nxt, vn0, vn1);                     // V regs -> LDS (loads have landed)
            tok_cur = tok_next;
        }
        __syncthreads();                                // drains K DMA (already landed)
    }

    auto finalize = [&](int ch, float l, float4v* O, int qt) {
        if (lane < 16) alph[ch][wv][lane] = l;
        const float4v lw = *(const float4v*)&alph[ch][wv][quad * 4];
#pragma unroll
        for (int j = 0; j < 4; ++j)
#pragma unroll
            for (int r = 0; r < 4; ++r) {
                const int qrow = qt * 64 + wv * 16 + quad * 4 + r;
                ctx[((size_t)b * TT + qrow) * DMODEL + h * DHEAD + j * 16 + l15] =
                    f2bf(O[j][r] / lw[r]);
            }
    };
    finalize(0, l0_, O0, qt0);
    finalize(1, l1_, O1, qt1);
}

// ---------------- host ----------------
extern "C" void kernel_launch(void* const* d_in, const int* in_sizes, int n_in,
                              void* d_out, int out_size, void* d_ws, size_t ws_size,
                              hipStream_t stream)
{
    const int* dec = (const int*)d_in[0];
    const int* enc = (const int*)d_in[1];
    const float* enc_out = (const float*)d_in[2];
    const float* emb = (const float*)d_in[3];
    const float* Wq_s = (const float*)d_in[4];
    const float* Wk_s = (const float*)d_in[5];
    const float* Wv_s = (const float*)d_in[6];
    const float* Wo_s = (const float*)d_in[7];
    const float* Wq_c = (const float*)d_in[8];
    const float* Wk_c = (const float*)d_in[9];
    const float* Wv_c = (const float*)d_in[10];
    const float* Wo_c = (const float*)d_in[11];
    const float* W1 = (const float*)d_in[12];
    const float* W2 = (const float*)d_in[13];
    float* out = (float*)d_out;

    char* p = (char*)d_ws;
    auto carve = [&](size_t bytes) -> char* {
        char* r = p;
        p += (bytes + 255) & ~(size_t)255;
        return r;
    };
    unsigned short* xb   = (unsigned short*)carve(ACTE * 2);
    float* tmp1          = (float*)carve(2 * ACTE * 4);           // 2 split-K partial slices
    unsigned short* qkvb = (unsigned short*)carve(3 * ACTE * 2);  // Q|K|V contiguous
    unsigned short* ctxb = (unsigned short*)carve(ACTE * 2);
    unsigned short* encb = (unsigned short*)carve(ACTE * 2);
    unsigned short* h1   = (unsigned short*)carve((size_t)NTOK * DFF * 2);
    unsigned short* wqkvT = (unsigned short*)carve((size_t)NLAYER * 1536 * 512 * 2);
    unsigned short* woT   = (unsigned short*)carve((size_t)NLAYER * 512 * 512 * 2);
    unsigned short* wqcT  = (unsigned short*)carve((size_t)NLAYER * 512 * 512 * 2);
    unsigned short* wkvcT = (unsigned short*)carve((size_t)NLAYER * 1024 * 512 * 2);
    unsigned short* wocT  = (unsigned short*)carve((size_t)NLAYER * 512 * 512 * 2);
    unsigned short* w1T   = (unsigned short*)carve((size_t)NLAYER * 2048 * 512 * 2);
    unsigned short* w2T   = (unsigned short*)carve((size_t)NLAYER * 512 * 2048 * 2);
    const size_t used = (size_t)(p - (char*)d_ws);
    const bool pre = (used + 12 * ACTE * 2 + 256) <= ws_size;  // all-layer cross K/V cache
    unsigned short* KVc = pre ? (unsigned short*)carve(12 * ACTE * 2) : nullptr;

    // weight prep: 8 small transposes merged into one dispatch
    Tr8Args ta;
    ta.src[0] = Wq_s; ta.dst[0] = wqkvT; ta.dstL[0] = 1536 * 512; ta.rowOff[0] = 0;
    ta.src[1] = Wk_s; ta.dst[1] = wqkvT; ta.dstL[1] = 1536 * 512; ta.rowOff[1] = 512;
    ta.src[2] = Wv_s; ta.dst[2] = wqkvT; ta.dstL[2] = 1536 * 512; ta.rowOff[2] = 1024;
    ta.src[3] = Wo_s; ta.dst[3] = woT;   ta.dstL[3] = 512 * 512;  ta.rowOff[3] = 0;
    ta.src[4] = Wq_c; ta.dst[4] = wqcT;  ta.dstL[4] = 512 * 512;  ta.rowOff[4] = 0;
    ta.src[5] = Wk_c; ta.dst[5] = wkvcT; ta.dstL[5] = 1024 * 512; ta.rowOff[5] = 0;
    ta.src[6] = Wv_c; ta.dst[6] = wkvcT; ta.dstL[6] = 1024 * 512; ta.rowOff[6] = 512;
    ta.src[7] = Wo_c; ta.dst[7] = wocT;  ta.dstL[7] = 512 * 512;  ta.rowOff[7] = 0;
    transpose8_kernel<<<dim3(8, 8, 48), 256, 0, stream>>>(ta);
    transpose_conv_kernel<<<dim3(8, 32, NLAYER), 256, 0, stream>>>(W1, w1T, 512, 2048, (size_t)2048 * 512, 0);
    transpose_conv_kernel<<<dim3(32, 8, NLAYER), 256, 0, stream>>>(W2, w2T, 2048, 512, (size_t)512 * 2048, 0);
    conv_bf16_kernel<<<(int)(ACTE / 1024), 256, 0, stream>>>(enc_out, encb);
    embed_kernel<<<NTOK, 256, 0, stream>>>(dec, emb, xb);

    // cross K/V for ALL layers in one big GEMM (enc side is layer-invariant)
    if (pre)
        gemm_bt<3><<<dim3(64, 48), 256, 0, stream>>>(encb, wkvcT, nullptr, KVc, NTOK, 6144, 512);

    for (int lyr = 0; lyr < NLAYER; ++lyr) {
        const unsigned short* wqkv = wqkvT + (size_t)lyr * 1536 * 512;
        const unsigned short* wo   = woT + (size_t)lyr * 512 * 512;
        const unsigned short* wqc  = wqcT + (size_t)lyr * 512 * 512;
        const unsigned short* wkvc = wkvcT + (size_t)lyr * 1024 * 512;
        const unsigned short* woc  = wocT + (size_t)lyr * 512 * 512;
        const unsigned short* w1   = w1T + (size_t)lyr * 2048 * 512;
        const unsigned short* w2   = w2T + (size_t)lyr * 512 * 2048;

        // ---- self attention ----
        gemm_bt<2><<<dim3(64, 12), 256, 0, stream>>>(xb, wqkv, nullptr, qkvb, NTOK, 1536, 512);
        attn_kernel<true><<<dim3(8, BB * NH), 256, 0, stream>>>(
            qkvb, qkvb + ACTE, qkvb + 2 * ACTE, dec, ctxb);
        gemm_bt<0, 2><<<dim3(64, 4, 2), 256, 0, stream>>>(ctxb, wo, tmp1, nullptr, NTOK, 512, 512);
        add_ln2<<<NTOK / 4, 256, 0, stream>>>(tmp1, xb, nullptr);

        // ---- cross attention ----
        gemm_bt<2><<<dim3(64, 4), 256, 0, stream>>>(xb, wqc, nullptr, qkvb, NTOK, 512, 512);
        const unsigned short* Kc;
        if (pre) {
            Kc = KVc + (size_t)lyr * 2 * ACTE;
        } else {
            gemm_bt<2><<<dim3(64, 8), 256, 0, stream>>>(encb, wkvc, nullptr, qkvb + ACTE, NTOK, 1024, 512);
            Kc = qkvb + ACTE;
        }
        attn_kernel<false><<<dim3(8, BB * NH), 256, 0, stream>>>(
            qkvb, Kc, Kc + ACTE, enc, ctxb);
        gemm_bt<0, 2><<<dim3(64, 4, 2), 256, 0, stream>>>(ctxb, woc, tmp1, nullptr, NTOK, 512, 512);
        add_ln2<<<NTOK / 4, 256, 0, stream>>>(tmp1, xb, nullptr);

        // ---- FFN ----
        gemm_bt<1><<<dim3(64, 16), 256, 0, stream>>>(xb, w1, nullptr, h1, NTOK, 2048, 512);
        gemm_bt<0, 2><<<dim3(64, 4, 2), 256, 0, stream>>>(h1, w2, tmp1, nullptr, NTOK, 512, 2048);
        add_ln2<<<NTOK / 4, 256, 0, stream>>>(tmp1, xb, (lyr == NLAYER - 1) ? out : nullptr);
    }
    (void)in_sizes; (void)n_in; (void)out_size;
}